// Round 1
// baseline (1533.574 us; speedup 1.0000x reference)
//
#include <hip/hip_runtime.h>
#include <hip/hip_bf16.h>

// Problem constants
#define BB   16
#define CC   256
#define HH   32
#define WW   32
#define KK   8192
#define NN   16384      // BB*HH*WW tokens
#define HWSZ 1024       // HH*WW

#define QE_SIZE  4194304            // NN*CC
#define LOSS_OFF QE_SIZE            // d_out[LOSS_OFF] = commit_loss
#define IDX_OFF  (QE_SIZE + 1)      // d_out[IDX_OFF .. +NN) = indices as float

// ---------------------------------------------------------------------------
// Kernel 1: codebook squared norms ||e_k||^2  (one wave per code)
// ---------------------------------------------------------------------------
__global__ __launch_bounds__(256) void norms_kernel(const float* __restrict__ cb,
                                                    float* __restrict__ norms) {
    int gid  = blockIdx.x * 256 + threadIdx.x;
    int code = gid >> 6;          // 4 waves/block, one code per wave
    int lane = gid & 63;
    float4 v = *(const float4*)(cb + code * CC + lane * 4);   // 64 lanes x 4 = 256
    float s = v.x * v.x + v.y * v.y + v.z * v.z + v.w * v.w;
    #pragma unroll
    for (int off = 32; off; off >>= 1) s += __shfl_down(s, off);
    if (lane == 0) norms[code] = s;
}

// ---------------------------------------------------------------------------
// Kernel 2: fused SGEMM (x . e^T) + running argmin over codes.
//   grid 256 blocks (1/CU), 256 threads. Each block: 64 tokens, all 8192 codes.
//   Tile: M=64 tokens, N=128 codes, Ktile=16 channels. Micro-tile 4x8.
//   d'(token,code) = ||e||^2 - 2*dot  (||x||^2 constant per token -> dropped)
// ---------------------------------------------------------------------------
__global__ __launch_bounds__(256) void argmin_kernel(const float* __restrict__ x,
                                                     const float* __restrict__ cb,
                                                     const float* __restrict__ norms,
                                                     int*   __restrict__ idx_i,
                                                     float* __restrict__ idx_f) {
    __shared__ float Asm[16][64];       // [c_local][token]  4 KB
    __shared__ float Bsm[16][128];      // [c_local][code]   8 KB
    __shared__ float nrm[128];
    __shared__ float cand_d[16][65];    // [tx][token], +1 pad kills 16-way conflict
    __shared__ int   cand_i[16][65];
    __shared__ float best_d[64];
    __shared__ int   best_i[64];

    const int t  = threadIdx.x;
    const int tx = t & 15;              // code group (x4, two halves)
    const int ty = t >> 4;              // token group (x4)
    const int n0 = blockIdx.x * 64;     // first token of this block
    const int b  = n0 >> 10;            // image index (64 | 1024 so single b)
    const int hw0 = n0 & 1023;
    const float* xbase = x + (b << 18) + hw0;   // + (c<<10) + tok addresses x[b][c][hw]

    if (t < 64) { best_d[t] = 1e30f; best_i[t] = 0; }

    // A loader: one float4; c_local = t>>4 (16), tok4 = t&15 (x4 = 64 tokens)
    const int a_c = t >> 4, a_t4 = t & 15;
    // B loader: two float4; code_local = t>>1 (128), c8 = (t&1)*8
    const int b_n = t >> 1, b_c8 = (t & 1) * 8;

    // register prefetch for k-tile q=0 (ct=0, kt=0)
    float4 pa  = *(const float4*)(xbase + (a_c << 10) + a_t4 * 4);
    float4 pb0, pb1;
    {
        const float* bp = cb + b_n * CC + b_c8;
        pb0 = *(const float4*)(bp);
        pb1 = *(const float4*)(bp + 4);
    }

    float acc[4][8];

    for (int ct = 0; ct < 64; ++ct) {               // 64 code tiles of 128
        const int code0 = ct * 128;
        #pragma unroll
        for (int i = 0; i < 4; ++i)
            #pragma unroll
            for (int j = 0; j < 8; ++j) acc[i][j] = 0.f;

        for (int kt = 0; kt < 16; ++kt) {           // 16 k-tiles of 16 channels
            __syncthreads();                        // prev compute/epilogue done
            // store staged tile (transpose B to [c][code])
            *(float4*)&Asm[a_c][a_t4 * 4] = pa;
            #pragma unroll
            for (int s = 0; s < 4; ++s) Bsm[b_c8 + s][b_n]     = (&pb0.x)[s];
            #pragma unroll
            for (int s = 0; s < 4; ++s) Bsm[b_c8 + 4 + s][b_n] = (&pb1.x)[s];
            if (kt == 0 && t < 128) nrm[t] = norms[code0 + t];
            __syncthreads();

            // prefetch next k-tile into registers (hides global latency)
            const int q = ct * 16 + kt + 1;
            if (q < 1024) {
                const int nct = q >> 4, nkt = q & 15;
                pa = *(const float4*)(xbase + ((nkt * 16 + a_c) << 10) + a_t4 * 4);
                const float* bp = cb + (nct * 128 + b_n) * CC + nkt * 16 + b_c8;
                pb0 = *(const float4*)(bp);
                pb1 = *(const float4*)(bp + 4);
            }

            // 16 k-steps x 32 FMA
            #pragma unroll
            for (int k = 0; k < 16; ++k) {
                float4 av  = *(const float4*)&Asm[k][ty * 4];
                float4 bv0 = *(const float4*)&Bsm[k][tx * 4];
                float4 bv1 = *(const float4*)&Bsm[k][64 + tx * 4];
                float aa[4] = {av.x, av.y, av.z, av.w};
                float bb[8] = {bv0.x, bv0.y, bv0.z, bv0.w,
                               bv1.x, bv1.y, bv1.z, bv1.w};
                #pragma unroll
                for (int i = 0; i < 4; ++i)
                    #pragma unroll
                    for (int j = 0; j < 8; ++j)
                        acc[i][j] += aa[i] * bb[j];
            }
        }

        // epilogue: distances + running argmin (strict < keeps first occurrence)
        #pragma unroll
        for (int i = 0; i < 4; ++i) {
            float bd = 1e30f; int bi = 0x7fffffff;
            #pragma unroll
            for (int j = 0; j < 8; ++j) {
                const int nloc = (j >> 2) * 64 + tx * 4 + (j & 3);  // ascending in j
                const float d = nrm[nloc] - 2.f * acc[i][j];
                const int gi = code0 + nloc;
                if (d < bd || (d == bd && gi < bi)) { bd = d; bi = gi; }
            }
            cand_d[tx][ty * 4 + i] = bd;
            cand_i[tx][ty * 4 + i] = bi;
        }
        __syncthreads();
        if (t < 64) {
            float bd = best_d[t]; int bi = best_i[t];
            #pragma unroll 4
            for (int u = 0; u < 16; ++u) {
                const float d = cand_d[u][t]; const int gi = cand_i[u][t];
                if (d < bd || (d == bd && gi < bi)) { bd = d; bi = gi; }
            }
            best_d[t] = bd; best_i[t] = bi;
        }
        // next iteration's first __syncthreads() fences cand reuse
    }

    if (t < 64) {
        idx_i[n0 + t] = best_i[t];
        idx_f[n0 + t] = (float)best_i[t];
    }
}

// ---------------------------------------------------------------------------
// Kernel 3: gather qe = codebook[idx] back to NCHW + commit loss reduction
// ---------------------------------------------------------------------------
__global__ __launch_bounds__(256) void gather_kernel(const float* __restrict__ x,
                                                     const float* __restrict__ cb,
                                                     const int* __restrict__ idx,
                                                     float* __restrict__ qe,
                                                     float* __restrict__ loss) {
    __shared__ int   rows[64];
    __shared__ float wsum[4];
    const int t  = threadIdx.x;
    const int n0 = blockIdx.x * 64;
    const int b  = n0 >> 10, hw0 = n0 & 1023;
    if (t < 64) rows[t] = idx[n0 + t];
    __syncthreads();
    const int tok = t & 63, cq = t >> 6;
    const int row = rows[tok];
    const float* xb  = x  + (b << 18) + hw0 + tok;
    float*       qb  = qe + (b << 18) + hw0 + tok;
    const float* cbr = cb + row * CC;
    float lsum = 0.f;
    #pragma unroll 4
    for (int c0 = 0; c0 < CC; c0 += 4) {
        const int c = c0 + cq;
        const float q  = cbr[c];
        const float xv = xb[c << 10];
        qb[c << 10] = q;
        const float d = xv - q;
        lsum += d * d;
    }
    #pragma unroll
    for (int off = 32; off; off >>= 1) lsum += __shfl_down(lsum, off);
    if ((t & 63) == 0) wsum[t >> 6] = lsum;
    __syncthreads();
    if (t == 0) {
        const float s = wsum[0] + wsum[1] + wsum[2] + wsum[3];
        atomicAdd(loss, s * (1.0f / ((float)NN * (float)CC)));
    }
}

// ---------------------------------------------------------------------------
extern "C" void kernel_launch(void* const* d_in, const int* in_sizes, int n_in,
                              void* d_out, int out_size, void* d_ws, size_t ws_size,
                              hipStream_t stream) {
    const float* x  = (const float*)d_in[0];   // [16,256,32,32]
    const float* cb = (const float*)d_in[1];   // [8192,256]
    float* out = (float*)d_out;

    float* nrm_ws = (float*)d_ws;                          // 8192 floats
    int*   idx_ws = (int*)((char*)d_ws + KK * sizeof(float)); // 16384 ints

    norms_kernel<<<KK / 4, 256, 0, stream>>>(cb, nrm_ws);
    argmin_kernel<<<NN / 64, 256, 0, stream>>>(x, cb, nrm_ws, idx_ws,
                                               out + IDX_OFF);
    hipMemsetAsync(out + LOSS_OFF, 0, sizeof(float), stream);
    gather_kernel<<<NN / 64, 256, 0, stream>>>(x, cb, idx_ws, out,
                                               out + LOSS_OFF);
}

// Round 4
// 796.370 us; speedup vs baseline: 1.9257x; 1.9257x over previous
//
#include <hip/hip_runtime.h>
#include <hip/hip_bf16.h>
#include <stdint.h>

// Problem constants
#define KK   8192
#define NN   16384      // B*H*W tokens
#define CCH  256        // channels

#define QE_SIZE  4194304            // NN*CCH floats
#define LOSS_OFF QE_SIZE
#define IDX_OFF  (QE_SIZE + 1)

// ws layout (bytes) — ~1.2 MB
#define HN_OFF     0ULL                              // float hn[8192]
#define P1D_OFF    (HN_OFF + 8192ULL*4)              // float pd1[4][16384]
#define P1I_OFF    (P1D_OFF + 4ULL*16384*4)          // int   pi1[4][16384]
#define P2D_OFF    (P1I_OFF + 4ULL*16384*4)          // float pd2[4][16384]
#define P2I_OFF    (P2D_OFF + 4ULL*16384*4)          // int   pi2[4][16384]
#define IDXW_OFF   (P2I_OFF + 4ULL*16384*4)          // int   idx[16384]

typedef __attribute__((ext_vector_type(8))) short   bf16x8;
typedef __attribute__((ext_vector_type(8))) unsigned short ushort8v;
typedef __attribute__((ext_vector_type(4))) float   f32x4;

__device__ __forceinline__ void gld16(const void* g, void* l) {
    __builtin_amdgcn_global_load_lds(
        (const __attribute__((address_space(1))) void*)g,
        (__attribute__((address_space(3))) void*)l, 16, 0, 0);
}

// round-to-nearest-even fp32 -> bf16 bits
__device__ __forceinline__ unsigned short bf16_rn(float v) {
    uint32_t u = __float_as_uint(v);
    return (unsigned short)((u + 0x7fffu + ((u >> 16) & 1u)) >> 16);
}

// merge other top-2 (t1,j1,t2,j2) into mine (s1,i1,s2,i2)
__device__ __forceinline__ void top2_merge(float& s1, int& i1, float& s2, int& i2,
                                           float t1, int j1, float t2, int j2) {
    if (t1 > s1 || (t1 == s1 && j1 < i1)) {
        // other's first wins; second = max(my first, other's second)
        float ns2; int ni2;
        if (s1 > t2 || (s1 == t2 && i1 < j2)) { ns2 = s1; ni2 = i1; }
        else                                   { ns2 = t2; ni2 = j2; }
        s1 = t1; i1 = j1; s2 = ns2; i2 = ni2;
    } else {
        if (t1 > s2 || (t1 == s2 && j1 < i2)) { s2 = t1; i2 = j1; }
    }
}

// ---------------------------------------------------------------------------
// Prep 1: split x [16,256,32,32] -> A2[n][512] = [hi(256) | lo(256)] (bf16),
// written into d_out's qe region (exactly 16 MiB; qe is rewritten last).
// ---------------------------------------------------------------------------
__global__ __launch_bounds__(256) void split_x_kernel(const float* __restrict__ x,
                                                      unsigned short* __restrict__ A) {
    __shared__ float xt[256 * 64];      // [c][tok] 64 KB
    const int t = threadIdx.x;
    const int n0 = blockIdx.x * 64;
    const int b = n0 >> 10, hw0 = n0 & 1023;
    const int tok_l = t & 63, cg = t >> 6;
    const float* xb = x + ((size_t)b << 18) + hw0 + tok_l;
    #pragma unroll 8
    for (int i = 0; i < 64; ++i) {
        int c = cg * 64 + i;
        xt[c * 64 + tok_l] = xb[(size_t)c << 10];
    }
    __syncthreads();
    const int tokq = t >> 5;            // 8 tokens per pass
    const int c8 = (t & 31) * 8;
    for (int p = 0; p < 8; ++p) {
        int tk = p * 8 + tokq;
        unsigned short hi[8], lo[8];
        #pragma unroll
        for (int u = 0; u < 8; ++u) {
            float v = xt[(c8 + u) * 64 + tk];
            unsigned short h = bf16_rn(v);
            float fh = __uint_as_float(((uint32_t)h) << 16);
            lo[u] = bf16_rn(v - fh);
            hi[u] = h;
        }
        unsigned short* Ar = A + (size_t)(n0 + tk) * 512;
        *(ushort8v*)(Ar + c8)       = *(ushort8v*)hi;
        *(ushort8v*)(Ar + 256 + c8) = *(ushort8v*)lo;
    }
}

// ---------------------------------------------------------------------------
// Prep 2: hn[k] = 0.5*||e_k||^2 (fp32 exact), one wave per code
// ---------------------------------------------------------------------------
__global__ __launch_bounds__(256) void norms_kernel(const float* __restrict__ cb,
                                                    float* __restrict__ hn) {
    int gid  = blockIdx.x * 256 + threadIdx.x;
    int code = gid >> 6;
    int lane = gid & 63;
    float4 v = *(const float4*)(cb + (size_t)code * CCH + lane * 4);
    float s = v.x * v.x + v.y * v.y + v.z * v.z + v.w * v.w;
    #pragma unroll
    for (int off = 32; off; off >>= 1) s += __shfl_down(s, off);
    if (lane == 0) hn[code] = 0.5f * s;
}

// ---------------------------------------------------------------------------
// Main: bf16 MFMA GEMM, fused TOP-2 of (dot - 0.5||e||^2) per token.
// Block: 128 tokens x 2048 codes (16 N-tiles of 128). Virtual K=768: per
// 64-ch slab: phase0 A_hi*B_hi, phase1 A_lo*B_hi (B reused), phase2 A_hi*B_lo.
// ---------------------------------------------------------------------------
__global__ __launch_bounds__(256) void vq_gemm_kernel(const unsigned short* __restrict__ A2,
                                                      const float* __restrict__ cb,
                                                      const float* __restrict__ hn,
                                                      float* __restrict__ pd1,
                                                      int*   __restrict__ pi1,
                                                      float* __restrict__ pd2,
                                                      int*   __restrict__ pi2) {
    __shared__ unsigned short Asm[128 * 64];   // 16 KB
    __shared__ unsigned short Bsm[128 * 64];   // 16 KB
    __shared__ float ls1[128]; __shared__ int li1[128];
    __shared__ float ls2[128]; __shared__ int li2[128];

    const int t = threadIdx.x;
    const int lane = t & 63, wave = t >> 6;
    const int wm = wave >> 1, wn = wave & 1;
    const int l15 = lane & 15, quad = lane >> 4;

    const int mtile = blockIdx.x & 127, nq = blockIdx.x >> 7;
    const int m0 = mtile * 128;
    const int codeQ = nq * 2048;

    // A staging geometry (global_load_lds: wave-uniform LDS base + lane*16)
    const int srow = wave * 8 + (lane >> 3);
    const int sch  = (lane & 7) ^ (srow & 7);
    const size_t aRow = (size_t)(m0 + srow) * 512 + sch * 8;
    char* const asBase = (char*)Asm + wave * 1024;

    // B conversion geometry
    const int brow = t >> 1;
    const int bc32 = (t & 1) * 32;

    // fragment-read geometry
    const int rowA = wm * 64 + l15;
    const int rowB = wn * 64 + l15;
    const int chA0 = quad ^ (rowA & 7);
    const int chB0 = quad ^ (rowB & 7);

    f32x4 acc[4][4];
    float rs1[4][4], rs2[4][4];
    int   ri1[4][4], ri2[4][4];
    #pragma unroll
    for (int i = 0; i < 4; ++i)
        #pragma unroll
        for (int r = 0; r < 4; ++r) {
            rs1[i][r] = -1e30f; ri1[i][r] = 0x7ffffff;
            rs2[i][r] = -1e30f; ri2[i][r] = 0x7ffffff;
        }

    for (int nt = 0; nt < 16; ++nt) {
        const int code0 = codeQ + nt * 128;
        const float* const bsrc = cb + (size_t)(code0 + brow) * 256 + bc32;
        #pragma unroll
        for (int i = 0; i < 4; ++i)
            #pragma unroll
            for (int j = 0; j < 4; ++j) {
                f32x4 z = {0.f, 0.f, 0.f, 0.f};
                acc[i][j] = z;
            }

        #pragma unroll
        for (int s = 0; s < 12; ++s) {
            const int slab  = s / 3;
            const int phase = s - 3 * slab;    // 0: hi, 1: reuse, 2: lo
            const int akt   = (phase == 1 ? 256 : 0) + slab * 64;

            float4 f[8];
            if (phase != 1) {
                const float4* s4 = (const float4*)(bsrc + slab * 64);
                #pragma unroll
                for (int u = 0; u < 8; ++u) f[u] = s4[u];
            }

            __syncthreads();
            #pragma unroll
            for (int it = 0; it < 4; ++it)
                gld16(A2 + aRow + (size_t)it * (32 * 512) + akt,
                      asBase + it * 4096);

            if (phase != 1) {
                unsigned short v[32];
                #pragma unroll
                for (int u = 0; u < 8; ++u) {
                    const float* fp = (const float*)&f[u];
                    #pragma unroll
                    for (int w = 0; w < 4; ++w) {
                        const float vv = fp[w];
                        unsigned short h = bf16_rn(vv);
                        if (phase == 0) {
                            v[u * 4 + w] = h;
                        } else {
                            float fh = __uint_as_float(((uint32_t)h) << 16);
                            v[u * 4 + w] = bf16_rn(vv - fh);
                        }
                    }
                }
                #pragma unroll
                for (int q = 0; q < 4; ++q) {
                    const int csrc = (bc32 >> 3) + q;
                    const int pos = csrc ^ (brow & 7);
                    *(ushort8v*)((char*)Bsm + brow * 128 + pos * 16) =
                        *(const ushort8v*)(v + q * 8);
                }
            }
            __syncthreads();

            #pragma unroll
            for (int ks = 0; ks < 2; ++ks) {
                bf16x8 af[4], bfr[4];
                const int ca  = (chA0 ^ (ks << 2)) * 16;
                const int cbk = (chB0 ^ (ks << 2)) * 16;
                #pragma unroll
                for (int i = 0; i < 4; ++i)
                    af[i] = *(const bf16x8*)((const char*)Asm + (rowA + i * 16) * 128 + ca);
                #pragma unroll
                for (int j = 0; j < 4; ++j)
                    bfr[j] = *(const bf16x8*)((const char*)Bsm + (rowB + j * 16) * 128 + cbk);
                #pragma unroll
                for (int i = 0; i < 4; ++i)
                    #pragma unroll
                    for (int j = 0; j < 4; ++j)
                        acc[i][j] = __builtin_amdgcn_mfma_f32_16x16x32_bf16(
                            af[i], bfr[j], acc[i][j], 0, 0, 0);
            }
        }

        // top-2 update (codes ascend over j,nt per lane)
        #pragma unroll
        for (int j = 0; j < 4; ++j) {
            const int cg = code0 + wn * 64 + j * 16 + l15;
            const float h = hn[cg];
            #pragma unroll
            for (int i = 0; i < 4; ++i)
                #pragma unroll
                for (int r = 0; r < 4; ++r) {
                    const float s = acc[i][j][r] - h;
                    if (s > rs1[i][r]) {
                        rs2[i][r] = rs1[i][r]; ri2[i][r] = ri1[i][r];
                        rs1[i][r] = s;         ri1[i][r] = cg;
                    } else if (s > rs2[i][r]) {
                        rs2[i][r] = s; ri2[i][r] = cg;
                    }
                }
        }
    }

    // cross-lane top-2 merge within 16-lane groups (same token rows)
    #pragma unroll
    for (int off = 1; off < 16; off <<= 1) {
        #pragma unroll
        for (int i = 0; i < 4; ++i)
            #pragma unroll
            for (int r = 0; r < 4; ++r) {
                const float t1 = __shfl_xor(rs1[i][r], off);
                const int   j1 = __shfl_xor(ri1[i][r], off);
                const float t2 = __shfl_xor(rs2[i][r], off);
                const int   j2 = __shfl_xor(ri2[i][r], off);
                top2_merge(rs1[i][r], ri1[i][r], rs2[i][r], ri2[i][r],
                           t1, j1, t2, j2);
            }
    }

    // merge the two wn-waves via LDS, write per-quarter top-2
    if (wn == 0 && l15 == 0) {
        #pragma unroll
        for (int i = 0; i < 4; ++i)
            #pragma unroll
            for (int r = 0; r < 4; ++r) {
                const int tl = wm * 64 + i * 16 + quad * 4 + r;
                ls1[tl] = rs1[i][r]; li1[tl] = ri1[i][r];
                ls2[tl] = rs2[i][r]; li2[tl] = ri2[i][r];
            }
    }
    __syncthreads();
    if (wn == 1 && l15 == 0) {
        #pragma unroll
        for (int i = 0; i < 4; ++i)
            #pragma unroll
            for (int r = 0; r < 4; ++r) {
                const int tl = wm * 64 + i * 16 + quad * 4 + r;
                float s1 = ls1[tl]; int i1 = li1[tl];
                float s2 = ls2[tl]; int i2 = li2[tl];
                top2_merge(s1, i1, s2, i2,
                           rs1[i][r], ri1[i][r], rs2[i][r], ri2[i][r]);
                const int g = nq * NN + m0 + tl;
                pd1[g] = s1; pi1[g] = i1;
                pd2[g] = s2; pi2[g] = i2;
            }
    }
}

// ---------------------------------------------------------------------------
// Merge 4 quarters' top-2 -> global top-2 -> exact fp64 rescore -> final idx.
// One wave per token.
// ---------------------------------------------------------------------------
__global__ __launch_bounds__(256) void rescore_kernel(const float* __restrict__ x,
                                                      const float* __restrict__ cb,
                                                      const float* __restrict__ pd1,
                                                      const int*   __restrict__ pi1,
                                                      const float* __restrict__ pd2,
                                                      const int*   __restrict__ pi2,
                                                      int* __restrict__ idx_i,
                                                      float* __restrict__ idx_f) {
    const int wave = threadIdx.x >> 6, lane = threadIdx.x & 63;
    const int n = blockIdx.x * 4 + wave;

    // merge quarters (all lanes redundantly; same-address loads broadcast)
    float s1 = -1e30f, s2 = -1e30f; int i1 = 0, i2 = 1;
    #pragma unroll
    for (int q = 0; q < 4; ++q) {
        const int g = q * NN + n;
        top2_merge(s1, i1, s2, i2, pd1[g], pi1[g], pd2[g], pi2[g]);
    }

    // exact distances in fp64
    const int b = n >> 10, hw = n & 1023;
    const float* xb = x + ((size_t)b << 18) + hw;
    const float* c1 = cb + (size_t)i1 * CCH;
    const float* c2 = cb + (size_t)i2 * CCH;
    double d1 = 0.0, d2 = 0.0;
    #pragma unroll
    for (int u = 0; u < 4; ++u) {
        const int c = u * 64 + lane;
        const double xv = (double)xb[(size_t)c << 10];
        const double e1 = (double)c1[c];
        const double e2 = (double)c2[c];
        d1 += (xv - e1) * (xv - e1);
        d2 += (xv - e2) * (xv - e2);
    }
    #pragma unroll
    for (int off = 32; off; off >>= 1) {
        d1 += __shfl_down(d1, off);
        d2 += __shfl_down(d2, off);
    }
    if (lane == 0) {
        const int best = (d2 < d1 || (d2 == d1 && i2 < i1)) ? i2 : i1;
        idx_i[n] = best;
        idx_f[n] = (float)best;
    }
}

// ---------------------------------------------------------------------------
// Gather qe = codebook[idx] (NCHW) + commit loss  (runs LAST: rewrites qe)
// ---------------------------------------------------------------------------
__global__ __launch_bounds__(256) void gather_kernel(const float* __restrict__ x,
                                                     const float* __restrict__ cb,
                                                     const int* __restrict__ idx,
                                                     float* __restrict__ qe,
                                                     float* __restrict__ loss) {
    __shared__ int   rows[64];
    __shared__ float wsum[4];
    const int t  = threadIdx.x;
    const int n0 = blockIdx.x * 64;
    const int b  = n0 >> 10, hw0 = n0 & 1023;
    if (t < 64) rows[t] = idx[n0 + t];
    __syncthreads();
    const int tok = t & 63, cq = t >> 6;
    const int row = rows[tok];
    const float* xb  = x  + ((size_t)b << 18) + hw0 + tok;
    float*       qb  = qe + ((size_t)b << 18) + hw0 + tok;
    const float* cbr = cb + (size_t)row * CCH;
    float lsum = 0.f;
    #pragma unroll 4
    for (int c0 = 0; c0 < CCH; c0 += 4) {
        const int c = c0 + cq;
        const float q  = cbr[c];
        const float xv = xb[(size_t)c << 10];
        qb[(size_t)c << 10] = q;
        const float d = xv - q;
        lsum += d * d;
    }
    #pragma unroll
    for (int off = 32; off; off >>= 1) lsum += __shfl_down(lsum, off);
    if ((t & 63) == 0) wsum[t >> 6] = lsum;
    __syncthreads();
    if (t == 0) {
        const float s = wsum[0] + wsum[1] + wsum[2] + wsum[3];
        atomicAdd(loss, s * (1.0f / ((float)NN * (float)CCH)));
    }
}

// ---------------------------------------------------------------------------
extern "C" void kernel_launch(void* const* d_in, const int* in_sizes, int n_in,
                              void* d_out, int out_size, void* d_ws, size_t ws_size,
                              hipStream_t stream) {
    const float* x  = (const float*)d_in[0];
    const float* cb = (const float*)d_in[1];
    float* out = (float*)d_out;
    char* ws = (char*)d_ws;

    // A2 lives in d_out's qe region (exactly 16 MiB); gather rewrites qe last.
    unsigned short* A2 = (unsigned short*)out;
    float* hn  = (float*)(ws + HN_OFF);
    float* pd1 = (float*)(ws + P1D_OFF);
    int*   pi1 = (int*)(ws + P1I_OFF);
    float* pd2 = (float*)(ws + P2D_OFF);
    int*   pi2 = (int*)(ws + P2I_OFF);
    int*   idx = (int*)(ws + IDXW_OFF);

    split_x_kernel <<<NN / 64, 256, 0, stream>>>(x, A2);
    norms_kernel   <<<KK / 4, 256, 0, stream>>>(cb, hn);
    vq_gemm_kernel <<<512, 256, 0, stream>>>(A2, cb, hn, pd1, pi1, pd2, pi2);
    rescore_kernel <<<NN / 4, 256, 0, stream>>>(x, cb, pd1, pi1, pd2, pi2,
                                                idx, out + IDX_OFF);
    hipMemsetAsync(out + LOSS_OFF, 0, sizeof(float), stream);
    gather_kernel  <<<NN / 64, 256, 0, stream>>>(x, cb, idx, out, out + LOSS_OFF);
}

// Round 5
// 578.497 us; speedup vs baseline: 2.6510x; 1.3766x over previous
//
#include <hip/hip_runtime.h>
#include <hip/hip_bf16.h>
#include <stdint.h>

// Problem constants
#define KK   8192
#define NN   16384      // B*H*W tokens
#define CCH  256        // channels

#define QE_SIZE  4194304            // NN*CCH floats
#define LOSS_OFF QE_SIZE
#define IDX_OFF  (QE_SIZE + 1)

// ws layout (bytes) — ~17.3 MB
#define B2_OFF     0ULL                              // ushort B2[8192][512] = [hi|lo]
#define HN_OFF     (B2_OFF + 8192ULL*512*2)          // float hn[8192]
#define P1D_OFF    (HN_OFF + 8192ULL*4)              // float pd1[4][16384]
#define P1I_OFF    (P1D_OFF + 4ULL*16384*4)          // int   pi1[4][16384]
#define P2D_OFF    (P1I_OFF + 4ULL*16384*4)          // float pd2[4][16384]
#define P2I_OFF    (P2D_OFF + 4ULL*16384*4)          // int   pi2[4][16384]
#define IDXW_OFF   (P2I_OFF + 4ULL*16384*4)          // int   idx[16384]

typedef __attribute__((ext_vector_type(8))) short   bf16x8;
typedef __attribute__((ext_vector_type(8))) unsigned short ushort8v;
typedef __attribute__((ext_vector_type(4))) float   f32x4;

__device__ __forceinline__ void gld16(const void* g, void* l) {
    __builtin_amdgcn_global_load_lds(
        (const __attribute__((address_space(1))) void*)g,
        (__attribute__((address_space(3))) void*)l, 16, 0, 0);
}

// round-to-nearest-even fp32 -> bf16 bits
__device__ __forceinline__ unsigned short bf16_rn(float v) {
    uint32_t u = __float_as_uint(v);
    return (unsigned short)((u + 0x7fffu + ((u >> 16) & 1u)) >> 16);
}

// merge other top-2 (t1,j1,t2,j2) into mine (s1,i1,s2,i2); higher score wins,
// ties -> smaller index (first-occurrence argmin semantics)
__device__ __forceinline__ void top2_merge(float& s1, int& i1, float& s2, int& i2,
                                           float t1, int j1, float t2, int j2) {
    if (t1 > s1 || (t1 == s1 && j1 < i1)) {
        float ns2; int ni2;
        if (s1 > t2 || (s1 == t2 && i1 < j2)) { ns2 = s1; ni2 = i1; }
        else                                   { ns2 = t2; ni2 = j2; }
        s1 = t1; i1 = j1; s2 = ns2; i2 = ni2;
    } else {
        if (t1 > s2 || (t1 == s2 && j1 < i2)) { s2 = t1; i2 = j1; }
    }
}

// ---------------------------------------------------------------------------
// Prep 1: split x [16,256,32,32] -> A2[n][512] = [hi(256) | lo(256)] (bf16),
// written into d_out's qe region (exactly 16 MiB; qe is rewritten last).
// ---------------------------------------------------------------------------
__global__ __launch_bounds__(256) void split_x_kernel(const float* __restrict__ x,
                                                      unsigned short* __restrict__ A) {
    __shared__ float xt[256 * 64];      // [c][tok] 64 KB
    const int t = threadIdx.x;
    const int n0 = blockIdx.x * 64;
    const int b = n0 >> 10, hw0 = n0 & 1023;
    const int tok_l = t & 63, cg = t >> 6;
    const float* xb = x + ((size_t)b << 18) + hw0 + tok_l;
    #pragma unroll 8
    for (int i = 0; i < 64; ++i) {
        int c = cg * 64 + i;
        xt[c * 64 + tok_l] = xb[(size_t)c << 10];
    }
    __syncthreads();
    const int tokq = t >> 5;            // 8 tokens per pass
    const int c8 = (t & 31) * 8;
    for (int p = 0; p < 8; ++p) {
        int tk = p * 8 + tokq;
        unsigned short hi[8], lo[8];
        #pragma unroll
        for (int u = 0; u < 8; ++u) {
            float v = xt[(c8 + u) * 64 + tk];
            unsigned short h = bf16_rn(v);
            float fh = __uint_as_float(((uint32_t)h) << 16);
            lo[u] = bf16_rn(v - fh);
            hi[u] = h;
        }
        unsigned short* Ar = A + (size_t)(n0 + tk) * 512;
        *(ushort8v*)(Ar + c8)       = *(ushort8v*)hi;
        *(ushort8v*)(Ar + 256 + c8) = *(ushort8v*)lo;
    }
}

// ---------------------------------------------------------------------------
// Prep 2: split codebook [8192][256] -> B2[k][512] = [hi | lo] (bf16) and
// hn[k] = 0.5*||e_k||^2 (fp32 exact). 32 threads per code row.
// ---------------------------------------------------------------------------
__global__ __launch_bounds__(256) void split_cb_kernel(const float* __restrict__ cb,
                                                       unsigned short* __restrict__ B2,
                                                       float* __restrict__ hn) {
    const int t = threadIdx.x;
    const int code = blockIdx.x * 8 + (t >> 5);
    const int c8 = (t & 31) * 8;
    const float* cr = cb + (size_t)code * CCH + c8;
    float s = 0.f;
    unsigned short hi[8], lo[8];
    #pragma unroll
    for (int u = 0; u < 8; ++u) {
        float v = cr[u];
        s += v * v;
        unsigned short h = bf16_rn(v);
        float fh = __uint_as_float(((uint32_t)h) << 16);
        lo[u] = bf16_rn(v - fh);
        hi[u] = h;
    }
    unsigned short* Br = B2 + (size_t)code * 512;
    *(ushort8v*)(Br + c8)       = *(ushort8v*)hi;
    *(ushort8v*)(Br + 256 + c8) = *(ushort8v*)lo;
    #pragma unroll
    for (int off = 16; off; off >>= 1) s += __shfl_xor(s, off);
    if ((t & 31) == 0) hn[code] = 0.5f * s;
}

// ---------------------------------------------------------------------------
// Main: bf16 MFMA GEMM, fused TOP-2 of (dot - 0.5||e||^2) per token.
// Block: 128 tokens x 2048 codes (16 N-tiles of 128). Virtual K=768 as
// 12 steps (4 slabs x 3 phases): A offsets {hi,lo,hi}, B offsets {hi,hi,lo}.
// Pure m97 K-loop: 8x global_load_lds(16B) + barrier + ds_read_b128 + MFMA.
// ---------------------------------------------------------------------------
__global__ __launch_bounds__(256) void vq_gemm_kernel(const unsigned short* __restrict__ A2,
                                                      const unsigned short* __restrict__ B2,
                                                      const float* __restrict__ hn,
                                                      float* __restrict__ pd1,
                                                      int*   __restrict__ pi1,
                                                      float* __restrict__ pd2,
                                                      int*   __restrict__ pi2) {
    __shared__ unsigned short Asm[128 * 64];   // 16 KB
    __shared__ unsigned short Bsm[128 * 64];   // 16 KB
    __shared__ float ls1[128]; __shared__ int li1[128];
    __shared__ float ls2[128]; __shared__ int li2[128];

    const int t = threadIdx.x;
    const int lane = t & 63, wave = t >> 6;
    const int wm = wave >> 1, wn = wave & 1;
    const int l15 = lane & 15, quad = lane >> 4;

    const int mtile = blockIdx.x & 127, nq = blockIdx.x >> 7;
    const int m0 = mtile * 128;
    const int codeQ = nq * 2048;

    // staging geometry (global_load_lds: wave-uniform LDS base + lane*16)
    const int srow = wave * 8 + (lane >> 3);           // + it*32
    const int sch  = (lane & 7) ^ (srow & 7);          // swizzled source chunk
    const size_t aRow = (size_t)(m0 + srow) * 512 + sch * 8;
    char* const asBase = (char*)Asm + wave * 1024;     // + it*4096
    char* const bsBase = (char*)Bsm + wave * 1024;

    // fragment-read geometry
    const int rowA = wm * 64 + l15;                    // + i*16
    const int rowB = wn * 64 + l15;                    // + j*16
    const int chA0 = quad ^ (rowA & 7);
    const int chB0 = quad ^ (rowB & 7);

    f32x4 acc[4][4];
    float rs1[4][4], rs2[4][4];
    int   ri1[4][4], ri2[4][4];
    #pragma unroll
    for (int i = 0; i < 4; ++i)
        #pragma unroll
        for (int r = 0; r < 4; ++r) {
            rs1[i][r] = -1e30f; ri1[i][r] = 0x7ffffff;
            rs2[i][r] = -1e30f; ri2[i][r] = 0x7ffffff;
        }

    for (int nt = 0; nt < 16; ++nt) {
        const int code0 = codeQ + nt * 128;
        const size_t bRow = (size_t)(code0 + srow) * 512 + sch * 8;
        #pragma unroll
        for (int i = 0; i < 4; ++i)
            #pragma unroll
            for (int j = 0; j < 4; ++j) {
                f32x4 z = {0.f, 0.f, 0.f, 0.f};
                acc[i][j] = z;
            }

        #pragma unroll
        for (int s = 0; s < 12; ++s) {
            const int slab  = s >> 2;              // wrong if 12/3 -> use /3
            const int slab3 = s / 3;
            const int phase = s - 3 * slab3;       // 0: hi*hi, 1: lo*hi, 2: hi*lo
            (void)slab;
            const int akt = (phase == 1 ? 256 : 0) + slab3 * 64;
            const int bkt = (phase == 2 ? 256 : 0) + slab3 * 64;

            __syncthreads();                       // prev step's LDS reads done
            #pragma unroll
            for (int it = 0; it < 4; ++it) {
                gld16(A2 + aRow + (size_t)it * (32 * 512) + akt,
                      asBase + it * 4096);
                gld16(B2 + bRow + (size_t)it * (32 * 512) + bkt,
                      bsBase + it * 4096);
            }
            __syncthreads();                       // drains gld16 (vmcnt@barrier)

            #pragma unroll
            for (int ks = 0; ks < 2; ++ks) {
                bf16x8 af[4], bfr[4];
                const int ca  = (chA0 ^ (ks << 2)) * 16;
                const int cbk = (chB0 ^ (ks << 2)) * 16;
                #pragma unroll
                for (int i = 0; i < 4; ++i)
                    af[i] = *(const bf16x8*)((const char*)Asm + (rowA + i * 16) * 128 + ca);
                #pragma unroll
                for (int j = 0; j < 4; ++j)
                    bfr[j] = *(const bf16x8*)((const char*)Bsm + (rowB + j * 16) * 128 + cbk);
                #pragma unroll
                for (int i = 0; i < 4; ++i)
                    #pragma unroll
                    for (int j = 0; j < 4; ++j)
                        acc[i][j] = __builtin_amdgcn_mfma_f32_16x16x32_bf16(
                            af[i], bfr[j], acc[i][j], 0, 0, 0);
            }
        }

        // top-2 update (codes ascend over j,nt per lane)
        #pragma unroll
        for (int j = 0; j < 4; ++j) {
            const int cg = code0 + wn * 64 + j * 16 + l15;
            const float h = hn[cg];
            #pragma unroll
            for (int i = 0; i < 4; ++i)
                #pragma unroll
                for (int r = 0; r < 4; ++r) {
                    const float s = acc[i][j][r] - h;
                    if (s > rs1[i][r]) {
                        rs2[i][r] = rs1[i][r]; ri2[i][r] = ri1[i][r];
                        rs1[i][r] = s;         ri1[i][r] = cg;
                    } else if (s > rs2[i][r]) {
                        rs2[i][r] = s; ri2[i][r] = cg;
                    }
                }
        }
    }

    // cross-lane top-2 merge within 16-lane groups (same token rows)
    #pragma unroll
    for (int off = 1; off < 16; off <<= 1) {
        #pragma unroll
        for (int i = 0; i < 4; ++i)
            #pragma unroll
            for (int r = 0; r < 4; ++r) {
                const float t1 = __shfl_xor(rs1[i][r], off);
                const int   j1 = __shfl_xor(ri1[i][r], off);
                const float t2 = __shfl_xor(rs2[i][r], off);
                const int   j2 = __shfl_xor(ri2[i][r], off);
                top2_merge(rs1[i][r], ri1[i][r], rs2[i][r], ri2[i][r],
                           t1, j1, t2, j2);
            }
    }

    // merge the two wn-waves via LDS, write per-quarter top-2
    if (wn == 0 && l15 == 0) {
        #pragma unroll
        for (int i = 0; i < 4; ++i)
            #pragma unroll
            for (int r = 0; r < 4; ++r) {
                const int tl = wm * 64 + i * 16 + quad * 4 + r;
                ls1[tl] = rs1[i][r]; li1[tl] = ri1[i][r];
                ls2[tl] = rs2[i][r]; li2[tl] = ri2[i][r];
            }
    }
    __syncthreads();
    if (wn == 1 && l15 == 0) {
        #pragma unroll
        for (int i = 0; i < 4; ++i)
            #pragma unroll
            for (int r = 0; r < 4; ++r) {
                const int tl = wm * 64 + i * 16 + quad * 4 + r;
                float s1 = ls1[tl]; int i1 = li1[tl];
                float s2 = ls2[tl]; int i2 = li2[tl];
                top2_merge(s1, i1, s2, i2,
                           rs1[i][r], ri1[i][r], rs2[i][r], ri2[i][r]);
                const int g = nq * NN + m0 + tl;
                pd1[g] = s1; pi1[g] = i1;
                pd2[g] = s2; pi2[g] = i2;
            }
    }
}

// ---------------------------------------------------------------------------
// Merge 4 quarters' top-2 -> global top-2 -> exact fp64 rescore -> final idx.
// One wave per token.
// ---------------------------------------------------------------------------
__global__ __launch_bounds__(256) void rescore_kernel(const float* __restrict__ x,
                                                      const float* __restrict__ cb,
                                                      const float* __restrict__ pd1,
                                                      const int*   __restrict__ pi1,
                                                      const float* __restrict__ pd2,
                                                      const int*   __restrict__ pi2,
                                                      int* __restrict__ idx_i,
                                                      float* __restrict__ idx_f) {
    const int wave = threadIdx.x >> 6, lane = threadIdx.x & 63;
    const int n = blockIdx.x * 4 + wave;

    float s1 = -1e30f, s2 = -1e30f; int i1 = 0, i2 = 1;
    #pragma unroll
    for (int q = 0; q < 4; ++q) {
        const int g = q * NN + n;
        top2_merge(s1, i1, s2, i2, pd1[g], pi1[g], pd2[g], pi2[g]);
    }

    // exact distances in fp64
    const int b = n >> 10, hw = n & 1023;
    const float* xb = x + ((size_t)b << 18) + hw;
    const float* c1 = cb + (size_t)i1 * CCH;
    const float* c2 = cb + (size_t)i2 * CCH;
    double d1 = 0.0, d2 = 0.0;
    #pragma unroll
    for (int u = 0; u < 4; ++u) {
        const int c = u * 64 + lane;
        const double xv = (double)xb[(size_t)c << 10];
        const double e1 = (double)c1[c];
        const double e2 = (double)c2[c];
        d1 += (xv - e1) * (xv - e1);
        d2 += (xv - e2) * (xv - e2);
    }
    #pragma unroll
    for (int off = 32; off; off >>= 1) {
        d1 += __shfl_down(d1, off);
        d2 += __shfl_down(d2, off);
    }
    if (lane == 0) {
        const int best = (d2 < d1 || (d2 == d1 && i2 < i1)) ? i2 : i1;
        idx_i[n] = best;
        idx_f[n] = (float)best;
    }
}

// ---------------------------------------------------------------------------
// Gather qe = codebook[idx] (NCHW) + commit loss  (runs LAST: rewrites qe)
// ---------------------------------------------------------------------------
__global__ __launch_bounds__(256) void gather_kernel(const float* __restrict__ x,
                                                     const float* __restrict__ cb,
                                                     const int* __restrict__ idx,
                                                     float* __restrict__ qe,
                                                     float* __restrict__ loss) {
    __shared__ int   rows[64];
    __shared__ float wsum[4];
    const int t  = threadIdx.x;
    const int n0 = blockIdx.x * 64;
    const int b  = n0 >> 10, hw0 = n0 & 1023;
    if (t < 64) rows[t] = idx[n0 + t];
    __syncthreads();
    const int tok = t & 63, cq = t >> 6;
    const int row = rows[tok];
    const float* xb  = x  + ((size_t)b << 18) + hw0 + tok;
    float*       qb  = qe + ((size_t)b << 18) + hw0 + tok;
    const float* cbr = cb + (size_t)row * CCH;
    float lsum = 0.f;
    #pragma unroll 4
    for (int c0 = 0; c0 < CCH; c0 += 4) {
        const int c = c0 + cq;
        const float q  = cbr[c];
        const float xv = xb[(size_t)c << 10];
        qb[(size_t)c << 10] = q;
        const float d = xv - q;
        lsum += d * d;
    }
    #pragma unroll
    for (int off = 32; off; off >>= 1) lsum += __shfl_down(lsum, off);
    if ((t & 63) == 0) wsum[t >> 6] = lsum;
    __syncthreads();
    if (t == 0) {
        const float s = wsum[0] + wsum[1] + wsum[2] + wsum[3];
        atomicAdd(loss, s * (1.0f / ((float)NN * (float)CCH)));
    }
}

// ---------------------------------------------------------------------------
extern "C" void kernel_launch(void* const* d_in, const int* in_sizes, int n_in,
                              void* d_out, int out_size, void* d_ws, size_t ws_size,
                              hipStream_t stream) {
    const float* x  = (const float*)d_in[0];
    const float* cb = (const float*)d_in[1];
    float* out = (float*)d_out;
    char* ws = (char*)d_ws;

    // A2 lives in d_out's qe region (exactly 16 MiB); gather rewrites qe last.
    unsigned short* A2 = (unsigned short*)out;
    unsigned short* B2 = (unsigned short*)(ws + B2_OFF);
    float* hn  = (float*)(ws + HN_OFF);
    float* pd1 = (float*)(ws + P1D_OFF);
    int*   pi1 = (int*)(ws + P1I_OFF);
    float* pd2 = (float*)(ws + P2D_OFF);
    int*   pi2 = (int*)(ws + P2I_OFF);
    int*   idx = (int*)(ws + IDXW_OFF);

    split_x_kernel <<<NN / 64, 256, 0, stream>>>(x, A2);
    split_cb_kernel<<<KK / 8, 256, 0, stream>>>(cb, B2, hn);
    vq_gemm_kernel <<<512, 256, 0, stream>>>(A2, B2, hn, pd1, pi1, pd2, pi2);
    rescore_kernel <<<NN / 4, 256, 0, stream>>>(x, cb, pd1, pi1, pd2, pi2,
                                                idx, out + IDX_OFF);
    hipMemsetAsync(out + LOSS_OFF, 0, sizeof(float), stream);
    gather_kernel  <<<NN / 64, 256, 0, stream>>>(x, cb, idx, out, out + LOSS_OFF);
}

// Round 6
// 373.694 us; speedup vs baseline: 4.1038x; 1.5481x over previous
//
#include <hip/hip_runtime.h>
#include <hip/hip_bf16.h>
#include <stdint.h>

// Problem constants
#define KK   8192
#define NN   16384      // B*H*W tokens
#define CCH  256        // channels

#define QE_SIZE  4194304            // NN*CCH floats
#define LOSS_OFF QE_SIZE
#define IDX_OFF  (QE_SIZE + 1)

// ws layout (bytes) — ~9.3 MB
#define B2_OFF     0ULL                              // ushort B2[8192][512] = [hi|lo]
#define HN_OFF     (B2_OFF + 8192ULL*512*2)          // float hn[8192]
#define P1D_OFF    (HN_OFF + 8192ULL*4)              // float pd1[4][16384]
#define P1I_OFF    (P1D_OFF + 4ULL*16384*4)          // int   pi1[4][16384]
#define P2D_OFF    (P1I_OFF + 4ULL*16384*4)          // float pd2[4][16384]
#define P2I_OFF    (P2D_OFF + 4ULL*16384*4)          // int   pi2[4][16384]
#define IDXW_OFF   (P2I_OFF + 4ULL*16384*4)          // int   idx[16384]

typedef __attribute__((ext_vector_type(8))) short   bf16x8;
typedef __attribute__((ext_vector_type(8))) unsigned short ushort8v;
typedef __attribute__((ext_vector_type(4))) float   f32x4;

__device__ __forceinline__ void gld16(const void* g, void* l) {
    __builtin_amdgcn_global_load_lds(
        (const __attribute__((address_space(1))) void*)g,
        (__attribute__((address_space(3))) void*)l, 16, 0, 0);
}

// round-to-nearest-even fp32 -> bf16 bits
__device__ __forceinline__ unsigned short bf16_rn(float v) {
    uint32_t u = __float_as_uint(v);
    return (unsigned short)((u + 0x7fffu + ((u >> 16) & 1u)) >> 16);
}

// merge other top-2 (t1,j1,t2,j2) into mine (s1,i1,s2,i2); higher score wins,
// ties -> smaller index (first-occurrence argmin semantics)
__device__ __forceinline__ void top2_merge(float& s1, int& i1, float& s2, int& i2,
                                           float t1, int j1, float t2, int j2) {
    if (t1 > s1 || (t1 == s1 && j1 < i1)) {
        float ns2; int ni2;
        if (s1 > t2 || (s1 == t2 && i1 < j2)) { ns2 = s1; ni2 = i1; }
        else                                   { ns2 = t2; ni2 = j2; }
        s1 = t1; i1 = j1; s2 = ns2; i2 = ni2;
    } else {
        if (t1 > s2 || (t1 == s2 && j1 < i2)) { s2 = t1; i2 = j1; }
    }
}

// ---------------------------------------------------------------------------
// Prep 1: split x -> A-FRAGMENT-MAJOR layout in d_out's qe region (16 MiB).
// Afrag element: for 16-token tile tb = n>>4, virtual k-step ks (0..15 over
// [hi 256 | lo 256]), lane l (0..63): 8 bf16 of token tb*16+(l&15),
// channels ks*32 + (l>>4)*8 .. +7.  Frag addr (elements) =
// ((tb*16 + ks)*64 + l)*8.  This makes the GEMM's A load one coalesced
// dwordx4 per lane per ks.
// ---------------------------------------------------------------------------
__global__ __launch_bounds__(256) void split_x_kernel(const float* __restrict__ x,
                                                      unsigned short* __restrict__ A) {
    __shared__ float xt[256 * 64];      // [c][tok] 64 KB
    const int t = threadIdx.x;
    const int n0 = blockIdx.x * 64;
    const int b = n0 >> 10, hw0 = n0 & 1023;
    const int tok_l = t & 63, cg = t >> 6;
    const float* xb = x + ((size_t)b << 18) + hw0 + tok_l;
    #pragma unroll 8
    for (int i = 0; i < 64; ++i) {
        int c = cg * 64 + i;
        xt[c * 64 + tok_l] = xb[(size_t)c << 10];
    }
    __syncthreads();
    const int tokq = t >> 5;            // 8 tokens per pass
    const int c8 = (t & 31) * 8;
    const int ksh = c8 >> 5;            // hi ks
    const int lq  = (c8 >> 3) & 3;      // quad within frag
    for (int p = 0; p < 8; ++p) {
        int tk = p * 8 + tokq;
        unsigned short hi[8], lo[8];
        #pragma unroll
        for (int u = 0; u < 8; ++u) {
            float v = xt[(c8 + u) * 64 + tk];
            unsigned short h = bf16_rn(v);
            float fh = __uint_as_float(((uint32_t)h) << 16);
            lo[u] = bf16_rn(v - fh);
            hi[u] = h;
        }
        const int n  = n0 + tk;
        const int tb = n >> 4;
        const int l  = (tk & 15) + 16 * lq;
        *(ushort8v*)(A + ((size_t)((tb * 16 + ksh)     * 64) + l) * 8) = *(ushort8v*)hi;
        *(ushort8v*)(A + ((size_t)((tb * 16 + 8 + ksh) * 64) + l) * 8) = *(ushort8v*)lo;
    }
}

// ---------------------------------------------------------------------------
// Prep 2: split codebook [8192][256] -> B2[k][512] = [hi | lo] (bf16) and
// hn[k] = 0.5*||e_k||^2 (fp32 exact). 32 threads per code row.
// ---------------------------------------------------------------------------
__global__ __launch_bounds__(256) void split_cb_kernel(const float* __restrict__ cb,
                                                       unsigned short* __restrict__ B2,
                                                       float* __restrict__ hn) {
    const int t = threadIdx.x;
    const int code = blockIdx.x * 8 + (t >> 5);
    const int c8 = (t & 31) * 8;
    const float* cr = cb + (size_t)code * CCH + c8;
    float s = 0.f;
    unsigned short hi[8], lo[8];
    #pragma unroll
    for (int u = 0; u < 8; ++u) {
        float v = cr[u];
        s += v * v;
        unsigned short h = bf16_rn(v);
        float fh = __uint_as_float(((uint32_t)h) << 16);
        lo[u] = bf16_rn(v - fh);
        hi[u] = h;
    }
    unsigned short* Br = B2 + (size_t)code * 512;
    *(ushort8v*)(Br + c8)       = *(ushort8v*)hi;
    *(ushort8v*)(Br + 256 + c8) = *(ushort8v*)lo;
    #pragma unroll
    for (int off = 16; off; off >>= 1) s += __shfl_xor(s, off);
    if ((t & 31) == 0) hn[code] = 0.5f * s;
}

// ---------------------------------------------------------------------------
// Main: bf16 MFMA GEMM, fused TOP-2 of (dot - 0.5||e||^2).
// Block = 64 tokens x 2048 codes (one quarter). Each wave owns 16 tokens with
// A fully resident in 64 VGPRs (16 frags). Per N-tile (128 codes): 8 B-slab
// stages (4 hi + 4 lo, 16 KB each) double-buffered in LDS; prefetch issued
// AFTER the barrier so it overlaps the current stage's MFMA.
// Virtual K=768: Bhi stage s -> Ahi_s*Bhi_s + Alo_s*Bhi_s; Blo stage s ->
// Ahi_s*Blo_s.
// ---------------------------------------------------------------------------
__global__ __launch_bounds__(256, 2) void vq_gemm_kernel(const unsigned short* __restrict__ A,
                                                         const unsigned short* __restrict__ B2,
                                                         const float* __restrict__ hn,
                                                         float* __restrict__ pd1,
                                                         int*   __restrict__ pi1,
                                                         float* __restrict__ pd2,
                                                         int*   __restrict__ pi2) {
    __shared__ unsigned short Bsm[2][128 * 64];   // 2 x 16 KB ping-pong

    const int t = threadIdx.x;
    const int lane = t & 63, wave = t >> 6;
    const int l15 = lane & 15, quad = lane >> 4;

    const int mblk = blockIdx.x & 255;        // 256 M-blocks of 64 tokens
    const int nq   = blockIdx.x >> 8;         // 4 code quarters
    const int codeQ = nq * 2048;

    // A fragments: 16 coalesced dwordx4 loads, resident for the whole kernel
    bf16x8 af[16];
    {
        const unsigned short* Abase =
            A + ((size_t)((mblk * 4 + wave) * 16) * 64 + lane) * 8;
        #pragma unroll
        for (int ks = 0; ks < 16; ++ks)
            af[ks] = *(const bf16x8*)(Abase + (size_t)ks * 64 * 8);
    }

    // B staging geometry (global_load_lds: wave-uniform base + lane*16)
    const int srow = wave * 8 + (lane >> 3);          // + it*32
    const int sch  = (lane & 7) ^ (srow & 7);         // swizzled source chunk

#define STAGE_LOAD(GN)                                                         \
    do {                                                                       \
        const int ntn = (GN) >> 3, stn = (GN) & 7;                             \
        const int bkt = (stn & 3) * 64 + (stn >> 2) * 256;                     \
        const size_t bOff = (size_t)(codeQ + ntn * 128 + srow) * 512           \
                            + sch * 8 + bkt;                                   \
        char* dst = (char*)Bsm[(GN) & 1] + wave * 1024;                        \
        _Pragma("unroll")                                                      \
        for (int it = 0; it < 4; ++it)                                         \
            gld16(B2 + bOff + (size_t)it * (32 * 512), dst + it * 4096);       \
    } while (0)

    float rs1[4], rs2[4];
    int   ri1[4], ri2[4];
    #pragma unroll
    for (int r = 0; r < 4; ++r) {
        rs1[r] = -1e30f; ri1[r] = 0x7ffffff;
        rs2[r] = -1e30f; ri2[r] = 0x7ffffff;
    }

    STAGE_LOAD(0);                                     // prologue prefetch
    int g = 0;

    #pragma unroll 1
    for (int nt = 0; nt < 16; ++nt) {
        const int code0 = codeQ + nt * 128;
        f32x4 acc[8];
        #pragma unroll
        for (int j = 0; j < 8; ++j) {
            f32x4 z = {0.f, 0.f, 0.f, 0.f};
            acc[j] = z;
        }

        #pragma unroll
        for (int st = 0; st < 8; ++st) {
            __syncthreads();                           // stage g drained; prev reads done
            if (g + 1 < 128) STAGE_LOAD(g + 1);        // prefetch under this stage's MFMA
            const char* bs = (const char*)Bsm[g & 1];

            #pragma unroll
            for (int ks2 = 0; ks2 < 2; ++ks2) {
                bf16x8 bfr[8];
                #pragma unroll
                for (int j = 0; j < 8; ++j) {
                    const int rowB = j * 16 + l15;
                    const int cbk = ((quad ^ (rowB & 7)) ^ (ks2 << 2)) * 16;
                    bfr[j] = *(const bf16x8*)(bs + rowB * 128 + cbk);
                }
                if (st < 4) {
                    const int ka = st * 2 + ks2;       // A hi
                    #pragma unroll
                    for (int j = 0; j < 8; ++j)
                        acc[j] = __builtin_amdgcn_mfma_f32_16x16x32_bf16(
                            af[ka], bfr[j], acc[j], 0, 0, 0);
                    const int kb = 8 + st * 2 + ks2;   // A lo
                    #pragma unroll
                    for (int j = 0; j < 8; ++j)
                        acc[j] = __builtin_amdgcn_mfma_f32_16x16x32_bf16(
                            af[kb], bfr[j], acc[j], 0, 0, 0);
                } else {
                    const int ka = (st - 4) * 2 + ks2; // A hi x B lo
                    #pragma unroll
                    for (int j = 0; j < 8; ++j)
                        acc[j] = __builtin_amdgcn_mfma_f32_16x16x32_bf16(
                            af[ka], bfr[j], acc[j], 0, 0, 0);
                }
            }
            ++g;
        }

        // epilogue: top-2 of s = dot - 0.5||e||^2 (strict >, codes ascend)
        #pragma unroll
        for (int j = 0; j < 8; ++j) {
            const int cg = code0 + j * 16 + l15;
            const float h = hn[cg];
            #pragma unroll
            for (int r = 0; r < 4; ++r) {
                const float s = acc[j][r] - h;
                if (s > rs1[r]) {
                    rs2[r] = rs1[r]; ri2[r] = ri1[r];
                    rs1[r] = s;      ri1[r] = cg;
                } else if (s > rs2[r]) {
                    rs2[r] = s; ri2[r] = cg;
                }
            }
        }
    }
#undef STAGE_LOAD

    // top-2 butterfly across the 16-lane col groups (same tokens)
    #pragma unroll
    for (int off = 1; off < 16; off <<= 1) {
        #pragma unroll
        for (int r = 0; r < 4; ++r) {
            const float t1 = __shfl_xor(rs1[r], off);
            const int   j1 = __shfl_xor(ri1[r], off);
            const float t2 = __shfl_xor(rs2[r], off);
            const int   j2 = __shfl_xor(ri2[r], off);
            top2_merge(rs1[r], ri1[r], rs2[r], ri2[r], t1, j1, t2, j2);
        }
    }

    // l15==0 lanes hold finals for tokens mblk*64 + wave*16 + quad*4 + r
    if (l15 == 0) {
        #pragma unroll
        for (int r = 0; r < 4; ++r) {
            const int tok = mblk * 64 + wave * 16 + quad * 4 + r;
            const int gi = nq * NN + tok;
            pd1[gi] = rs1[r]; pi1[gi] = ri1[r];
            pd2[gi] = rs2[r]; pi2[gi] = ri2[r];
        }
    }
}

// ---------------------------------------------------------------------------
// Merge 4 quarters' top-2 -> global top-2 -> exact fp64 rescore -> final idx.
// One wave per token.
// ---------------------------------------------------------------------------
__global__ __launch_bounds__(256) void rescore_kernel(const float* __restrict__ x,
                                                      const float* __restrict__ cb,
                                                      const float* __restrict__ pd1,
                                                      const int*   __restrict__ pi1,
                                                      const float* __restrict__ pd2,
                                                      const int*   __restrict__ pi2,
                                                      int* __restrict__ idx_i,
                                                      float* __restrict__ idx_f) {
    const int wave = threadIdx.x >> 6, lane = threadIdx.x & 63;
    const int n = blockIdx.x * 4 + wave;

    float s1 = -1e30f, s2 = -1e30f; int i1 = 0, i2 = 1;
    #pragma unroll
    for (int q = 0; q < 4; ++q) {
        const int g = q * NN + n;
        top2_merge(s1, i1, s2, i2, pd1[g], pi1[g], pd2[g], pi2[g]);
    }

    // exact distances in fp64
    const int b = n >> 10, hw = n & 1023;
    const float* xb = x + ((size_t)b << 18) + hw;
    const float* c1 = cb + (size_t)i1 * CCH;
    const float* c2 = cb + (size_t)i2 * CCH;
    double d1 = 0.0, d2 = 0.0;
    #pragma unroll
    for (int u = 0; u < 4; ++u) {
        const int c = u * 64 + lane;
        const double xv = (double)xb[(size_t)c << 10];
        const double e1 = (double)c1[c];
        const double e2 = (double)c2[c];
        d1 += (xv - e1) * (xv - e1);
        d2 += (xv - e2) * (xv - e2);
    }
    #pragma unroll
    for (int off = 32; off; off >>= 1) {
        d1 += __shfl_down(d1, off);
        d2 += __shfl_down(d2, off);
    }
    if (lane == 0) {
        const int best = (d2 < d1 || (d2 == d1 && i2 < i1)) ? i2 : i1;
        idx_i[n] = best;
        idx_f[n] = (float)best;
    }
}

// ---------------------------------------------------------------------------
// Gather qe = codebook[idx] (NCHW) + commit loss  (runs LAST: rewrites qe)
// ---------------------------------------------------------------------------
__global__ __launch_bounds__(256) void gather_kernel(const float* __restrict__ x,
                                                     const float* __restrict__ cb,
                                                     const int* __restrict__ idx,
                                                     float* __restrict__ qe,
                                                     float* __restrict__ loss) {
    __shared__ int   rows[64];
    __shared__ float wsum[4];
    const int t  = threadIdx.x;
    const int n0 = blockIdx.x * 64;
    const int b  = n0 >> 10, hw0 = n0 & 1023;
    if (t < 64) rows[t] = idx[n0 + t];
    __syncthreads();
    const int tok = t & 63, cq = t >> 6;
    const int row = rows[tok];
    const float* xb  = x  + ((size_t)b << 18) + hw0 + tok;
    float*       qb  = qe + ((size_t)b << 18) + hw0 + tok;
    const float* cbr = cb + (size_t)row * CCH;
    float lsum = 0.f;
    #pragma unroll 4
    for (int c0 = 0; c0 < CCH; c0 += 4) {
        const int c = c0 + cq;
        const float q  = cbr[c];
        const float xv = xb[(size_t)c << 10];
        qb[(size_t)c << 10] = q;
        const float d = xv - q;
        lsum += d * d;
    }
    #pragma unroll
    for (int off = 32; off; off >>= 1) lsum += __shfl_down(lsum, off);
    if ((t & 63) == 0) wsum[t >> 6] = lsum;
    __syncthreads();
    if (t == 0) {
        const float s = wsum[0] + wsum[1] + wsum[2] + wsum[3];
        atomicAdd(loss, s * (1.0f / ((float)NN * (float)CCH)));
    }
}

// ---------------------------------------------------------------------------
extern "C" void kernel_launch(void* const* d_in, const int* in_sizes, int n_in,
                              void* d_out, int out_size, void* d_ws, size_t ws_size,
                              hipStream_t stream) {
    const float* x  = (const float*)d_in[0];
    const float* cb = (const float*)d_in[1];
    float* out = (float*)d_out;
    char* ws = (char*)d_ws;

    // A (frag-major) lives in d_out's qe region (16 MiB); gather rewrites qe last.
    unsigned short* A  = (unsigned short*)out;
    unsigned short* B2 = (unsigned short*)(ws + B2_OFF);
    float* hn  = (float*)(ws + HN_OFF);
    float* pd1 = (float*)(ws + P1D_OFF);
    int*   pi1 = (int*)(ws + P1I_OFF);
    float* pd2 = (float*)(ws + P2D_OFF);
    int*   pi2 = (int*)(ws + P2I_OFF);
    int*   idx = (int*)(ws + IDXW_OFF);

    split_x_kernel <<<NN / 64, 256, 0, stream>>>(x, A);
    split_cb_kernel<<<KK / 8, 256, 0, stream>>>(cb, B2, hn);
    vq_gemm_kernel <<<1024, 256, 0, stream>>>(A, B2, hn, pd1, pi1, pd2, pi2);
    rescore_kernel <<<NN / 4, 256, 0, stream>>>(x, cb, pd1, pi1, pd2, pi2,
                                                idx, out + IDX_OFF);
    hipMemsetAsync(out + LOSS_OFF, 0, sizeof(float), stream);
    gather_kernel  <<<NN / 64, 256, 0, stream>>>(x, cb, idx, out, out + LOSS_OFF);
}

// Round 7
// 367.449 us; speedup vs baseline: 4.1736x; 1.0170x over previous
//
#include <hip/hip_runtime.h>
#include <hip/hip_bf16.h>
#include <stdint.h>

// Problem constants
#define KK   8192
#define NN   16384      // B*H*W tokens
#define CCH  256        // channels

#define QE_SIZE  4194304            // NN*CCH floats
#define LOSS_OFF QE_SIZE
#define IDX_OFF  (QE_SIZE + 1)

// ws layout (bytes) — ~9.3 MB
#define B2_OFF     0ULL                              // ushort B2[8192][512] = [hi|lo]
#define HN_OFF     (B2_OFF + 8192ULL*512*2)          // float hn[8192]
#define P1D_OFF    (HN_OFF + 8192ULL*4)              // float pd1[4][16384]
#define P1I_OFF    (P1D_OFF + 4ULL*16384*4)          // int   pi1[4][16384]
#define P2D_OFF    (P1I_OFF + 4ULL*16384*4)          // float pd2[4][16384]
#define P2I_OFF    (P2D_OFF + 4ULL*16384*4)          // int   pi2[4][16384]

typedef __attribute__((ext_vector_type(8))) short   bf16x8;
typedef __attribute__((ext_vector_type(8))) unsigned short ushort8v;
typedef __attribute__((ext_vector_type(4))) float   f32x4;

__device__ __forceinline__ void gld16(const void* g, void* l) {
    __builtin_amdgcn_global_load_lds(
        (const __attribute__((address_space(1))) void*)g,
        (__attribute__((address_space(3))) void*)l, 16, 0, 0);
}

// round-to-nearest-even fp32 -> bf16 bits
__device__ __forceinline__ unsigned short bf16_rn(float v) {
    uint32_t u = __float_as_uint(v);
    return (unsigned short)((u + 0x7fffu + ((u >> 16) & 1u)) >> 16);
}

// merge other top-2 (t1,j1,t2,j2) into mine (s1,i1,s2,i2); higher score wins,
// ties -> smaller index (first-occurrence argmin semantics)
__device__ __forceinline__ void top2_merge(float& s1, int& i1, float& s2, int& i2,
                                           float t1, int j1, float t2, int j2) {
    if (t1 > s1 || (t1 == s1 && j1 < i1)) {
        float ns2; int ni2;
        if (s1 > t2 || (s1 == t2 && i1 < j2)) { ns2 = s1; ni2 = i1; }
        else                                   { ns2 = t2; ni2 = j2; }
        s1 = t1; i1 = j1; s2 = ns2; i2 = ni2;
    } else {
        if (t1 > s2 || (t1 == s2 && j1 < i2)) { s2 = t1; i2 = j1; }
    }
}

// ---------------------------------------------------------------------------
// Prep 1: split x -> A-FRAGMENT-MAJOR layout in d_out's qe region (16 MiB).
// For 16-token tile tb = n>>4, virtual k-step ks (0..15 over [hi|lo]),
// lane l: 8 bf16 of token tb*16+(l&15), channels ks*32 + (l>>4)*8.
// Frag addr (elements) = ((tb*16 + ks)*64 + l)*8.
// ---------------------------------------------------------------------------
__global__ __launch_bounds__(256) void split_x_kernel(const float* __restrict__ x,
                                                      unsigned short* __restrict__ A) {
    __shared__ float xt[256 * 64];      // [c][tok] 64 KB
    const int t = threadIdx.x;
    const int n0 = blockIdx.x * 64;
    const int b = n0 >> 10, hw0 = n0 & 1023;
    const int tok_l = t & 63, cg = t >> 6;
    const float* xb = x + ((size_t)b << 18) + hw0 + tok_l;
    #pragma unroll 8
    for (int i = 0; i < 64; ++i) {
        int c = cg * 64 + i;
        xt[c * 64 + tok_l] = xb[(size_t)c << 10];
    }
    __syncthreads();
    const int tokq = t >> 5;            // 8 tokens per pass
    const int c8 = (t & 31) * 8;
    const int ksh = c8 >> 5;            // hi ks
    const int lq  = (c8 >> 3) & 3;      // quad within frag
    for (int p = 0; p < 8; ++p) {
        int tk = p * 8 + tokq;
        unsigned short hi[8], lo[8];
        #pragma unroll
        for (int u = 0; u < 8; ++u) {
            float v = xt[(c8 + u) * 64 + tk];
            unsigned short h = bf16_rn(v);
            float fh = __uint_as_float(((uint32_t)h) << 16);
            lo[u] = bf16_rn(v - fh);
            hi[u] = h;
        }
        const int n  = n0 + tk;
        const int tb = n >> 4;
        const int l  = (tk & 15) + 16 * lq;
        *(ushort8v*)(A + ((size_t)((tb * 16 + ksh)     * 64) + l) * 8) = *(ushort8v*)hi;
        *(ushort8v*)(A + ((size_t)((tb * 16 + 8 + ksh) * 64) + l) * 8) = *(ushort8v*)lo;
    }
}

// ---------------------------------------------------------------------------
// Prep 2: split codebook [8192][256] -> B2[k][512] = [hi | lo] (bf16) and
// hn[k] = 0.5*||e_k||^2 (fp32 exact). 32 threads per code row.
// ---------------------------------------------------------------------------
__global__ __launch_bounds__(256) void split_cb_kernel(const float* __restrict__ cb,
                                                       unsigned short* __restrict__ B2,
                                                       float* __restrict__ hn) {
    const int t = threadIdx.x;
    const int code = blockIdx.x * 8 + (t >> 5);
    const int c8 = (t & 31) * 8;
    const float* cr = cb + (size_t)code * CCH + c8;
    float s = 0.f;
    unsigned short hi[8], lo[8];
    #pragma unroll
    for (int u = 0; u < 8; ++u) {
        float v = cr[u];
        s += v * v;
        unsigned short h = bf16_rn(v);
        float fh = __uint_as_float(((uint32_t)h) << 16);
        lo[u] = bf16_rn(v - fh);
        hi[u] = h;
    }
    unsigned short* Br = B2 + (size_t)code * 512;
    *(ushort8v*)(Br + c8)       = *(ushort8v*)hi;
    *(ushort8v*)(Br + 256 + c8) = *(ushort8v*)lo;
    #pragma unroll
    for (int off = 16; off; off >>= 1) s += __shfl_xor(s, off);
    if ((t & 31) == 0) hn[code] = 0.5f * s;
}

// ---------------------------------------------------------------------------
// Main: bf16 MFMA GEMM, fused TOP-2 of (dot - 0.5||e||^2).
// Block = 128 tokens x 2048 codes (one quarter); wave owns 32 tokens with A
// resident in 128 VGPRs (2 tiles x 16 frags). Per N-tile (128 codes): 8
// B-slab stages (4 hi + 4 lo, 16 KB each) double-buffered in LDS; prefetch
// issued after the barrier so it flies under the stage's MFMA. Each B-frag
// LDS read feeds 4 MFMAs (i0/i1 x Ahi/Alo) in hi-stages, 2 in lo-stages.
// ---------------------------------------------------------------------------
__global__ __launch_bounds__(256, 2) void vq_gemm_kernel(const unsigned short* __restrict__ A,
                                                         const unsigned short* __restrict__ B2,
                                                         const float* __restrict__ hn,
                                                         float* __restrict__ pd1,
                                                         int*   __restrict__ pi1,
                                                         float* __restrict__ pd2,
                                                         int*   __restrict__ pi2) {
    __shared__ unsigned short Bsm[2][128 * 64];   // 2 x 16 KB ping-pong

    const int t = threadIdx.x;
    const int lane = t & 63, wave = t >> 6;
    const int l15 = lane & 15, quad = lane >> 4;

    const int mblk = blockIdx.x & 127;        // 128 M-blocks of 128 tokens
    const int nq   = blockIdx.x >> 7;         // 4 code quarters
    const int codeQ = nq * 2048;

    // A fragments: 32 coalesced dwordx4 loads, resident for the whole kernel
    bf16x8 af[2][16];
    #pragma unroll
    for (int i = 0; i < 2; ++i) {
        const int tb = mblk * 8 + wave * 2 + i;   // 16-token tile id
        const unsigned short* Abase = A + ((size_t)(tb * 16) * 64 + lane) * 8;
        #pragma unroll
        for (int ks = 0; ks < 16; ++ks)
            af[i][ks] = *(const bf16x8*)(Abase + (size_t)ks * 64 * 8);
    }

    // B staging geometry (global_load_lds: wave-uniform base + lane*16)
    const int srow = wave * 8 + (lane >> 3);          // + it*32
    const int sch  = (lane & 7) ^ (srow & 7);         // swizzled source chunk

#define STAGE_LOAD(GN)                                                         \
    do {                                                                       \
        const int ntn = (GN) >> 3, stn = (GN) & 7;                             \
        const int bkt = (stn & 3) * 64 + (stn >> 2) * 256;                     \
        const size_t bOff = (size_t)(codeQ + ntn * 128 + srow) * 512           \
                            + sch * 8 + bkt;                                   \
        char* dst = (char*)Bsm[(GN) & 1] + wave * 1024;                        \
        _Pragma("unroll")                                                      \
        for (int it = 0; it < 4; ++it)                                         \
            gld16(B2 + bOff + (size_t)it * (32 * 512), dst + it * 4096);       \
    } while (0)

    float rs1[2][4], rs2[2][4];
    int   ri1[2][4], ri2[2][4];
    #pragma unroll
    for (int i = 0; i < 2; ++i)
        #pragma unroll
        for (int r = 0; r < 4; ++r) {
            rs1[i][r] = -1e30f; ri1[i][r] = 0x7ffffff;
            rs2[i][r] = -1e30f; ri2[i][r] = 0x7ffffff;
        }

    STAGE_LOAD(0);                                     // prologue prefetch
    int g = 0;

    #pragma unroll 1
    for (int nt = 0; nt < 16; ++nt) {
        const int code0 = codeQ + nt * 128;
        f32x4 acc[2][8];
        #pragma unroll
        for (int i = 0; i < 2; ++i)
            #pragma unroll
            for (int j = 0; j < 8; ++j) {
                f32x4 z = {0.f, 0.f, 0.f, 0.f};
                acc[i][j] = z;
            }

        #pragma unroll
        for (int st = 0; st < 8; ++st) {
            __syncthreads();                           // stage g drained; prev reads done
            if (g + 1 < 128) STAGE_LOAD(g + 1);        // prefetch under this stage's MFMA
            const char* bs = (const char*)Bsm[g & 1];

            #pragma unroll
            for (int ks2 = 0; ks2 < 2; ++ks2) {
                bf16x8 bfr[8];
                #pragma unroll
                for (int j = 0; j < 8; ++j) {
                    const int rowB = j * 16 + l15;
                    const int cbk = ((quad ^ (rowB & 7)) ^ (ks2 << 2)) * 16;
                    bfr[j] = *(const bf16x8*)(bs + rowB * 128 + cbk);
                }
                if (st < 4) {
                    const int ka = st * 2 + ks2;       // A hi + A lo vs B hi
                    #pragma unroll
                    for (int i = 0; i < 2; ++i) {
                        #pragma unroll
                        for (int j = 0; j < 8; ++j)
                            acc[i][j] = __builtin_amdgcn_mfma_f32_16x16x32_bf16(
                                af[i][ka], bfr[j], acc[i][j], 0, 0, 0);
                        #pragma unroll
                        for (int j = 0; j < 8; ++j)
                            acc[i][j] = __builtin_amdgcn_mfma_f32_16x16x32_bf16(
                                af[i][8 + ka], bfr[j], acc[i][j], 0, 0, 0);
                    }
                } else {
                    const int ka = (st - 4) * 2 + ks2; // A hi vs B lo
                    #pragma unroll
                    for (int i = 0; i < 2; ++i)
                        #pragma unroll
                        for (int j = 0; j < 8; ++j)
                            acc[i][j] = __builtin_amdgcn_mfma_f32_16x16x32_bf16(
                                af[i][ka], bfr[j], acc[i][j], 0, 0, 0);
                }
            }
            ++g;
        }

        // epilogue: top-2 of s = dot - 0.5||e||^2 (strict >, codes ascend)
        #pragma unroll
        for (int j = 0; j < 8; ++j) {
            const int cg = code0 + j * 16 + l15;
            const float h = hn[cg];
            #pragma unroll
            for (int i = 0; i < 2; ++i)
                #pragma unroll
                for (int r = 0; r < 4; ++r) {
                    const float s = acc[i][j][r] - h;
                    if (s > rs1[i][r]) {
                        rs2[i][r] = rs1[i][r]; ri2[i][r] = ri1[i][r];
                        rs1[i][r] = s;         ri1[i][r] = cg;
                    } else if (s > rs2[i][r]) {
                        rs2[i][r] = s; ri2[i][r] = cg;
                    }
                }
        }
    }
#undef STAGE_LOAD

    // top-2 butterfly across the 16-lane col groups (same tokens)
    #pragma unroll
    for (int off = 1; off < 16; off <<= 1) {
        #pragma unroll
        for (int i = 0; i < 2; ++i)
            #pragma unroll
            for (int r = 0; r < 4; ++r) {
                const float t1 = __shfl_xor(rs1[i][r], off);
                const int   j1 = __shfl_xor(ri1[i][r], off);
                const float t2 = __shfl_xor(rs2[i][r], off);
                const int   j2 = __shfl_xor(ri2[i][r], off);
                top2_merge(rs1[i][r], ri1[i][r], rs2[i][r], ri2[i][r],
                           t1, j1, t2, j2);
            }
    }

    // l15==0 lanes hold finals for tokens mblk*128 + wave*32 + i*16 + quad*4 + r
    if (l15 == 0) {
        #pragma unroll
        for (int i = 0; i < 2; ++i)
            #pragma unroll
            for (int r = 0; r < 4; ++r) {
                const int tok = mblk * 128 + wave * 32 + i * 16 + quad * 4 + r;
                const int gi = nq * NN + tok;
                pd1[gi] = rs1[i][r]; pi1[gi] = ri1[i][r];
                pd2[gi] = rs2[i][r]; pi2[gi] = ri2[i][r];
            }
    }
}

// ---------------------------------------------------------------------------
// Finalize (fused): merge 4 quarters' top-2 -> fp64 rescore -> best idx ->
// write qe (NCHW gather) + idx_f + commit-loss. One wave per token; x/e
// values stay in registers between rescore and qe-write.
// ---------------------------------------------------------------------------
__global__ __launch_bounds__(256) void finalize_kernel(const float* __restrict__ x,
                                                       const float* __restrict__ cb,
                                                       const float* __restrict__ pd1,
                                                       const int*   __restrict__ pi1,
                                                       const float* __restrict__ pd2,
                                                       const int*   __restrict__ pi2,
                                                       float* __restrict__ qe,
                                                       float* __restrict__ idx_f,
                                                       float* __restrict__ loss) {
    __shared__ float wsum[4];
    const int wave = threadIdx.x >> 6, lane = threadIdx.x & 63;
    const int n = blockIdx.x * 4 + wave;

    float s1 = -1e30f, s2 = -1e30f; int i1 = 0, i2 = 1;
    #pragma unroll
    for (int q = 0; q < 4; ++q) {
        const int g = q * NN + n;
        top2_merge(s1, i1, s2, i2, pd1[g], pi1[g], pd2[g], pi2[g]);
    }

    const int b = n >> 10, hw = n & 1023;
    const float* xb = x + ((size_t)b << 18) + hw;
    const float* c1 = cb + (size_t)i1 * CCH;
    const float* c2 = cb + (size_t)i2 * CCH;

    float xv[4], e1v[4], e2v[4];
    double d1 = 0.0, d2 = 0.0;
    #pragma unroll
    for (int u = 0; u < 4; ++u) {
        const int c = u * 64 + lane;
        xv[u]  = xb[(size_t)c << 10];
        e1v[u] = c1[c];
        e2v[u] = c2[c];
        const double dx1 = (double)xv[u] - (double)e1v[u];
        const double dx2 = (double)xv[u] - (double)e2v[u];
        d1 += dx1 * dx1;
        d2 += dx2 * dx2;
    }
    #pragma unroll
    for (int off = 32; off; off >>= 1) {       // butterfly: all lanes get sums
        d1 += __shfl_xor(d1, off);
        d2 += __shfl_xor(d2, off);
    }
    const bool pick2 = (d2 < d1 || (d2 == d1 && i2 < i1));
    const int best = pick2 ? i2 : i1;

    float* qb = qe + ((size_t)b << 18) + hw;
    float lsum = 0.f;
    #pragma unroll
    for (int u = 0; u < 4; ++u) {
        const int c = u * 64 + lane;
        const float q = pick2 ? e2v[u] : e1v[u];
        qb[(size_t)c << 10] = q;
        const float d = xv[u] - q;
        lsum += d * d;
    }
    if (lane == 0) idx_f[n] = (float)best;
    #pragma unroll
    for (int off = 32; off; off >>= 1) lsum += __shfl_down(lsum, off);
    if (lane == 0) wsum[wave] = lsum;
    __syncthreads();
    if (threadIdx.x == 0) {
        const float s = wsum[0] + wsum[1] + wsum[2] + wsum[3];
        atomicAdd(loss, s * (1.0f / ((float)NN * (float)CCH)));
    }
}

// ---------------------------------------------------------------------------
extern "C" void kernel_launch(void* const* d_in, const int* in_sizes, int n_in,
                              void* d_out, int out_size, void* d_ws, size_t ws_size,
                              hipStream_t stream) {
    const float* x  = (const float*)d_in[0];
    const float* cb = (const float*)d_in[1];
    float* out = (float*)d_out;
    char* ws = (char*)d_ws;

    // A (frag-major) lives in d_out's qe region (16 MiB); finalize rewrites qe.
    unsigned short* A  = (unsigned short*)out;
    unsigned short* B2 = (unsigned short*)(ws + B2_OFF);
    float* hn  = (float*)(ws + HN_OFF);
    float* pd1 = (float*)(ws + P1D_OFF);
    int*   pi1 = (int*)(ws + P1I_OFF);
    float* pd2 = (float*)(ws + P2D_OFF);
    int*   pi2 = (int*)(ws + P2I_OFF);

    split_x_kernel <<<NN / 64, 256, 0, stream>>>(x, A);
    split_cb_kernel<<<KK / 8, 256, 0, stream>>>(cb, B2, hn);
    vq_gemm_kernel <<<512, 256, 0, stream>>>(A, B2, hn, pd1, pi1, pd2, pi2);
    hipMemsetAsync(out + LOSS_OFF, 0, sizeof(float), stream);
    finalize_kernel<<<NN / 4, 256, 0, stream>>>(x, cb, pd1, pi1, pd2, pi2,
                                                out, out + IDX_OFF,
                                                out + LOSS_OFF);
}

// Round 8
// 344.332 us; speedup vs baseline: 4.4538x; 1.0671x over previous
//
#include <hip/hip_runtime.h>
#include <hip/hip_bf16.h>
#include <stdint.h>

// Problem constants
#define KK   8192
#define NN   16384      // B*H*W tokens
#define CCH  256        // channels

#define QE_SIZE  4194304            // NN*CCH floats
#define LOSS_OFF QE_SIZE
#define IDX_OFF  (QE_SIZE + 1)

// ws layout (bytes) — ~9.3 MB
#define B2_OFF     0ULL                              // ushort B2[8192][512] = [hi|lo]
#define HN_OFF     (B2_OFF + 8192ULL*512*2)          // float hn[8192]
#define P1D_OFF    (HN_OFF + 8192ULL*4)              // float pd1[4][16384]
#define P1I_OFF    (P1D_OFF + 4ULL*16384*4)          // int   pi1[4][16384]
#define P2D_OFF    (P1I_OFF + 4ULL*16384*4)          // float pd2[4][16384]
#define P2I_OFF    (P2D_OFF + 4ULL*16384*4)          // int   pi2[4][16384]

typedef __attribute__((ext_vector_type(8))) short   bf16x8;
typedef __attribute__((ext_vector_type(8))) unsigned short ushort8v;
typedef __attribute__((ext_vector_type(4))) float   f32x4;

__device__ __forceinline__ void gld16(const void* g, void* l) {
    __builtin_amdgcn_global_load_lds(
        (const __attribute__((address_space(1))) void*)g,
        (__attribute__((address_space(3))) void*)l, 16, 0, 0);
}

// round-to-nearest-even fp32 -> bf16 bits
__device__ __forceinline__ unsigned short bf16_rn(float v) {
    uint32_t u = __float_as_uint(v);
    return (unsigned short)((u + 0x7fffu + ((u >> 16) & 1u)) >> 16);
}

// merge other top-2 (t1,j1,t2,j2) into mine (s1,i1,s2,i2); higher score wins,
// ties -> smaller index (first-occurrence argmin semantics)
__device__ __forceinline__ void top2_merge(float& s1, int& i1, float& s2, int& i2,
                                           float t1, int j1, float t2, int j2) {
    if (t1 > s1 || (t1 == s1 && j1 < i1)) {
        float ns2; int ni2;
        if (s1 > t2 || (s1 == t2 && i1 < j2)) { ns2 = s1; ni2 = i1; }
        else                                   { ns2 = t2; ni2 = j2; }
        s1 = t1; i1 = j1; s2 = ns2; i2 = ni2;
    } else {
        if (t1 > s2 || (t1 == s2 && j1 < i2)) { s2 = t1; i2 = j1; }
    }
}

// ---------------------------------------------------------------------------
// Prep 1: split x -> A-FRAGMENT-MAJOR layout in d_out's qe region (16 MiB).
// For 16-token tile tb = n>>4, virtual k-step ks (0..15 over [hi|lo]),
// lane l: 8 bf16 of token tb*16+(l&15), channels ks*32 + (l>>4)*8.
// Frag addr (elements) = ((tb*16 + ks)*64 + l)*8.
// ---------------------------------------------------------------------------
__global__ __launch_bounds__(256) void split_x_kernel(const float* __restrict__ x,
                                                      unsigned short* __restrict__ A) {
    __shared__ float xt[256 * 64];      // [c][tok] 64 KB
    const int t = threadIdx.x;
    const int n0 = blockIdx.x * 64;
    const int b = n0 >> 10, hw0 = n0 & 1023;
    const int tok_l = t & 63, cg = t >> 6;
    const float* xb = x + ((size_t)b << 18) + hw0 + tok_l;
    #pragma unroll 8
    for (int i = 0; i < 64; ++i) {
        int c = cg * 64 + i;
        xt[c * 64 + tok_l] = xb[(size_t)c << 10];
    }
    __syncthreads();
    const int tokq = t >> 5;            // 8 tokens per pass
    const int c8 = (t & 31) * 8;
    const int ksh = c8 >> 5;            // hi ks
    const int lq  = (c8 >> 3) & 3;      // quad within frag
    for (int p = 0; p < 8; ++p) {
        int tk = p * 8 + tokq;
        unsigned short hi[8], lo[8];
        #pragma unroll
        for (int u = 0; u < 8; ++u) {
            float v = xt[(c8 + u) * 64 + tk];
            unsigned short h = bf16_rn(v);
            float fh = __uint_as_float(((uint32_t)h) << 16);
            lo[u] = bf16_rn(v - fh);
            hi[u] = h;
        }
        const int n  = n0 + tk;
        const int tb = n >> 4;
        const int l  = (tk & 15) + 16 * lq;
        *(ushort8v*)(A + ((size_t)((tb * 16 + ksh)     * 64) + l) * 8) = *(ushort8v*)hi;
        *(ushort8v*)(A + ((size_t)((tb * 16 + 8 + ksh) * 64) + l) * 8) = *(ushort8v*)lo;
    }
}

// ---------------------------------------------------------------------------
// Prep 2: split codebook [8192][256] -> B2[k][512] = [hi | lo] (bf16) and
// hn[k] = 0.5*||e_k||^2 (fp32 exact). 32 threads per code row.
// ---------------------------------------------------------------------------
__global__ __launch_bounds__(256) void split_cb_kernel(const float* __restrict__ cb,
                                                       unsigned short* __restrict__ B2,
                                                       float* __restrict__ hn) {
    const int t = threadIdx.x;
    const int code = blockIdx.x * 8 + (t >> 5);
    const int c8 = (t & 31) * 8;
    const float* cr = cb + (size_t)code * CCH + c8;
    float s = 0.f;
    unsigned short hi[8], lo[8];
    #pragma unroll
    for (int u = 0; u < 8; ++u) {
        float v = cr[u];
        s += v * v;
        unsigned short h = bf16_rn(v);
        float fh = __uint_as_float(((uint32_t)h) << 16);
        lo[u] = bf16_rn(v - fh);
        hi[u] = h;
    }
    unsigned short* Br = B2 + (size_t)code * 512;
    *(ushort8v*)(Br + c8)       = *(ushort8v*)hi;
    *(ushort8v*)(Br + 256 + c8) = *(ushort8v*)lo;
    #pragma unroll
    for (int off = 16; off; off >>= 1) s += __shfl_xor(s, off);
    if ((t & 31) == 0) hn[code] = 0.5f * s;
}

// ---------------------------------------------------------------------------
// Main: bf16 MFMA GEMM, fused TOP-2 of (dot - 0.5||e||^2).
// Block = 128 tokens x 2048 codes (one quarter); wave owns 32 tokens with A
// resident in 128 regs (2 tiles x 16 frags, AGPR-eligible). N-tile = 64
// codes: acc[2][4]=32 regs, bfr[4]=16 -> peak ~210 regs, NO SPILL at
// 2 blocks/CU. Per N-tile: 8 B-slab stages (4 hi + 4 lo, 8 KB each) double-
// buffered; prefetch issued after the barrier, flies under the MFMA phase.
// Each B-frag LDS read feeds 4 MFMAs (i0/i1 x Ahi/Alo) in hi-stages.
// ---------------------------------------------------------------------------
__global__ __launch_bounds__(256, 2) void vq_gemm_kernel(const unsigned short* __restrict__ A,
                                                         const unsigned short* __restrict__ B2,
                                                         const float* __restrict__ hn,
                                                         float* __restrict__ pd1,
                                                         int*   __restrict__ pi1,
                                                         float* __restrict__ pd2,
                                                         int*   __restrict__ pi2) {
    __shared__ unsigned short Bsm[2][64 * 64];    // 2 x 8 KB ping-pong

    const int t = threadIdx.x;
    const int lane = t & 63, wave = t >> 6;
    const int l15 = lane & 15, quad = lane >> 4;

    const int mblk = blockIdx.x & 127;        // 128 M-blocks of 128 tokens
    const int nq   = blockIdx.x >> 7;         // 4 code quarters
    const int codeQ = nq * 2048;

    // A fragments: 32 coalesced dwordx4 loads, resident for the whole kernel
    bf16x8 af[2][16];
    #pragma unroll
    for (int i = 0; i < 2; ++i) {
        const int tb = mblk * 8 + wave * 2 + i;   // 16-token tile id
        const unsigned short* Abase = A + ((size_t)(tb * 16) * 64 + lane) * 8;
        #pragma unroll
        for (int ks = 0; ks < 16; ++ks)
            af[i][ks] = *(const bf16x8*)(Abase + (size_t)ks * 64 * 8);
    }

    // B staging geometry (global_load_lds: wave-uniform base + lane*16)
    const int srow = wave * 8 + (lane >> 3);          // + it*32
    const int sch  = (lane & 7) ^ (srow & 7);         // swizzled source chunk

    // stage GN (0..255): ntn = GN>>3 (64-code tile), stn = GN&7
    // stn 0-3: B hi slabs (ch 0/64/128/192); stn 4-7: B lo slabs
#define STAGE_LOAD(GN)                                                         \
    do {                                                                       \
        const int ntn = (GN) >> 3, stn = (GN) & 7;                             \
        const int bkt = (stn & 3) * 64 + (stn >> 2) * 256;                     \
        const size_t bOff = (size_t)(codeQ + ntn * 64 + srow) * 512            \
                            + sch * 8 + bkt;                                   \
        char* dst = (char*)Bsm[(GN) & 1] + wave * 1024;                        \
        _Pragma("unroll")                                                      \
        for (int it = 0; it < 2; ++it)                                         \
            gld16(B2 + bOff + (size_t)it * (32 * 512), dst + it * 4096);       \
    } while (0)

    float rs1[2][4], rs2[2][4];
    int   ri1[2][4], ri2[2][4];
    #pragma unroll
    for (int i = 0; i < 2; ++i)
        #pragma unroll
        for (int r = 0; r < 4; ++r) {
            rs1[i][r] = -1e30f; ri1[i][r] = 0x7ffffff;
            rs2[i][r] = -1e30f; ri2[i][r] = 0x7ffffff;
        }

    STAGE_LOAD(0);                                     // prologue prefetch
    int g = 0;

    #pragma unroll 1
    for (int nt = 0; nt < 32; ++nt) {
        const int code0 = codeQ + nt * 64;
        f32x4 acc[2][4];
        #pragma unroll
        for (int i = 0; i < 2; ++i)
            #pragma unroll
            for (int j = 0; j < 4; ++j) {
                f32x4 z = {0.f, 0.f, 0.f, 0.f};
                acc[i][j] = z;
            }

        #pragma unroll
        for (int st = 0; st < 8; ++st) {
            __syncthreads();                           // stage g drained; prev reads done
            if (g + 1 < 256) STAGE_LOAD(g + 1);        // prefetch under this stage's MFMA
            const char* bs = (const char*)Bsm[g & 1];

            #pragma unroll
            for (int ks2 = 0; ks2 < 2; ++ks2) {
                bf16x8 bfr[4];
                #pragma unroll
                for (int j = 0; j < 4; ++j) {
                    const int rowB = j * 16 + l15;
                    const int cbk = ((quad ^ (rowB & 7)) ^ (ks2 << 2)) * 16;
                    bfr[j] = *(const bf16x8*)(bs + rowB * 128 + cbk);
                }
                if (st < 4) {
                    const int ka = st * 2 + ks2;       // A hi + A lo vs B hi
                    #pragma unroll
                    for (int i = 0; i < 2; ++i) {
                        #pragma unroll
                        for (int j = 0; j < 4; ++j)
                            acc[i][j] = __builtin_amdgcn_mfma_f32_16x16x32_bf16(
                                af[i][ka], bfr[j], acc[i][j], 0, 0, 0);
                        #pragma unroll
                        for (int j = 0; j < 4; ++j)
                            acc[i][j] = __builtin_amdgcn_mfma_f32_16x16x32_bf16(
                                af[i][8 + ka], bfr[j], acc[i][j], 0, 0, 0);
                    }
                } else {
                    const int ka = (st - 4) * 2 + ks2; // A hi vs B lo
                    #pragma unroll
                    for (int i = 0; i < 2; ++i)
                        #pragma unroll
                        for (int j = 0; j < 4; ++j)
                            acc[i][j] = __builtin_amdgcn_mfma_f32_16x16x32_bf16(
                                af[i][ka], bfr[j], acc[i][j], 0, 0, 0);
                }
            }
            ++g;
        }

        // epilogue: top-2 of s = dot - 0.5||e||^2 (strict >, codes ascend)
        #pragma unroll
        for (int j = 0; j < 4; ++j) {
            const int cg = code0 + j * 16 + l15;
            const float h = hn[cg];
            #pragma unroll
            for (int i = 0; i < 2; ++i)
                #pragma unroll
                for (int r = 0; r < 4; ++r) {
                    const float s = acc[i][j][r] - h;
                    if (s > rs1[i][r]) {
                        rs2[i][r] = rs1[i][r]; ri2[i][r] = ri1[i][r];
                        rs1[i][r] = s;         ri1[i][r] = cg;
                    } else if (s > rs2[i][r]) {
                        rs2[i][r] = s; ri2[i][r] = cg;
                    }
                }
        }
    }
#undef STAGE_LOAD

    // top-2 butterfly across the 16-lane col groups (same tokens)
    #pragma unroll
    for (int off = 1; off < 16; off <<= 1) {
        #pragma unroll
        for (int i = 0; i < 2; ++i)
            #pragma unroll
            for (int r = 0; r < 4; ++r) {
                const float t1 = __shfl_xor(rs1[i][r], off);
                const int   j1 = __shfl_xor(ri1[i][r], off);
                const float t2 = __shfl_xor(rs2[i][r], off);
                const int   j2 = __shfl_xor(ri2[i][r], off);
                top2_merge(rs1[i][r], ri1[i][r], rs2[i][r], ri2[i][r],
                           t1, j1, t2, j2);
            }
    }

    // l15==0 lanes hold finals for tokens mblk*128 + wave*32 + i*16 + quad*4 + r
    if (l15 == 0) {
        #pragma unroll
        for (int i = 0; i < 2; ++i)
            #pragma unroll
            for (int r = 0; r < 4; ++r) {
                const int tok = mblk * 128 + wave * 32 + i * 16 + quad * 4 + r;
                const int gi = nq * NN + tok;
                pd1[gi] = rs1[i][r]; pi1[gi] = ri1[i][r];
                pd2[gi] = rs2[i][r]; pi2[gi] = ri2[i][r];
            }
    }
}

// ---------------------------------------------------------------------------
// Finalize (fused): merge 4 quarters' top-2 -> fp64 rescore -> best idx ->
// write qe (NCHW gather) + idx_f + commit-loss. One wave per token; x/e
// values stay in registers between rescore and qe-write.
// ---------------------------------------------------------------------------
__global__ __launch_bounds__(256) void finalize_kernel(const float* __restrict__ x,
                                                       const float* __restrict__ cb,
                                                       const float* __restrict__ pd1,
                                                       const int*   __restrict__ pi1,
                                                       const float* __restrict__ pd2,
                                                       const int*   __restrict__ pi2,
                                                       float* __restrict__ qe,
                                                       float* __restrict__ idx_f,
                                                       float* __restrict__ loss) {
    __shared__ float wsum[4];
    const int wave = threadIdx.x >> 6, lane = threadIdx.x & 63;
    const int n = blockIdx.x * 4 + wave;

    float s1 = -1e30f, s2 = -1e30f; int i1 = 0, i2 = 1;
    #pragma unroll
    for (int q = 0; q < 4; ++q) {
        const int g = q * NN + n;
        top2_merge(s1, i1, s2, i2, pd1[g], pi1[g], pd2[g], pi2[g]);
    }

    const int b = n >> 10, hw = n & 1023;
    const float* xb = x + ((size_t)b << 18) + hw;
    const float* c1 = cb + (size_t)i1 * CCH;
    const float* c2 = cb + (size_t)i2 * CCH;

    float xv[4], e1v[4], e2v[4];
    double d1 = 0.0, d2 = 0.0;
    #pragma unroll
    for (int u = 0; u < 4; ++u) {
        const int c = u * 64 + lane;
        xv[u]  = xb[(size_t)c << 10];
        e1v[u] = c1[c];
        e2v[u] = c2[c];
        const double dx1 = (double)xv[u] - (double)e1v[u];
        const double dx2 = (double)xv[u] - (double)e2v[u];
        d1 += dx1 * dx1;
        d2 += dx2 * dx2;
    }
    #pragma unroll
    for (int off = 32; off; off >>= 1) {       // butterfly: all lanes get sums
        d1 += __shfl_xor(d1, off);
        d2 += __shfl_xor(d2, off);
    }
    const bool pick2 = (d2 < d1 || (d2 == d1 && i2 < i1));
    const int best = pick2 ? i2 : i1;

    float* qb = qe + ((size_t)b << 18) + hw;
    float lsum = 0.f;
    #pragma unroll
    for (int u = 0; u < 4; ++u) {
        const int c = u * 64 + lane;
        const float q = pick2 ? e2v[u] : e1v[u];
        qb[(size_t)c << 10] = q;
        const float d = xv[u] - q;
        lsum += d * d;
    }
    if (lane == 0) idx_f[n] = (float)best;
    #pragma unroll
    for (int off = 32; off; off >>= 1) lsum += __shfl_down(lsum, off);
    if (lane == 0) wsum[wave] = lsum;
    __syncthreads();
    if (threadIdx.x == 0) {
        const float s = wsum[0] + wsum[1] + wsum[2] + wsum[3];
        atomicAdd(loss, s * (1.0f / ((float)NN * (float)CCH)));
    }
}

// ---------------------------------------------------------------------------
extern "C" void kernel_launch(void* const* d_in, const int* in_sizes, int n_in,
                              void* d_out, int out_size, void* d_ws, size_t ws_size,
                              hipStream_t stream) {
    const float* x  = (const float*)d_in[0];
    const float* cb = (const float*)d_in[1];
    float* out = (float*)d_out;
    char* ws = (char*)d_ws;

    // A (frag-major) lives in d_out's qe region (16 MiB); finalize rewrites qe.
    unsigned short* A  = (unsigned short*)out;
    unsigned short* B2 = (unsigned short*)(ws + B2_OFF);
    float* hn  = (float*)(ws + HN_OFF);
    float* pd1 = (float*)(ws + P1D_OFF);
    int*   pi1 = (int*)(ws + P1I_OFF);
    float* pd2 = (float*)(ws + P2D_OFF);
    int*   pi2 = (int*)(ws + P2I_OFF);

    split_x_kernel <<<NN / 64, 256, 0, stream>>>(x, A);
    split_cb_kernel<<<KK / 8, 256, 0, stream>>>(cb, B2, hn);
    vq_gemm_kernel <<<512, 256, 0, stream>>>(A, B2, hn, pd1, pi1, pd2, pi2);
    hipMemsetAsync(out + LOSS_OFF, 0, sizeof(float), stream);
    finalize_kernel<<<NN / 4, 256, 0, stream>>>(x, cb, pd1, pi1, pd2, pi2,
                                                out, out + IDX_OFF,
                                                out + LOSS_OFF);
}